// Round 5
// baseline (510.384 us; speedup 1.0000x reference)
//
#include <hip/hip_runtime.h>

#define N_NODES 100000
#define N_EDGES 1600000
#define N_GRAPH 1024
#define NB      196      // buckets of 512 nodes
#define BCAP    10240    // bucket capacity (mean 8192, ~22 sigma slack)
#define PEPT    16       // edges per thread in partition

typedef unsigned short u16;
typedef unsigned int   u32;

__device__ __forceinline__ float sigm(float z) { return 1.0f / (1.0f + __expf(-z)); }
__device__ __forceinline__ u16 f2bf(float f) {
    u32 u = __float_as_uint(f);
    u += 0x7FFFu + ((u >> 16) & 1u);
    return (u16)(u >> 16);
}
__device__ __forceinline__ float bf2f(u16 h) { return __uint_as_float(((u32)h) << 16); }

// ======================= CSR build: bucket partition =======================
__global__ __launch_bounds__(256) void k_partition(const int* __restrict__ ei,
                                                   int* __restrict__ gcnt,
                                                   int* __restrict__ bucketed)
{
    __shared__ int lcnt[NB], gbase[NB], lcur[NB];
    int t = threadIdx.x;
    for (int i = t; i < NB; i += 256) { lcnt[i] = 0; lcur[i] = 0; }
    __syncthreads();

    int ebase = blockIdx.x * (256 * PEPT);
    int pk[PEPT], bk[PEPT];
#pragma unroll
    for (int r = 0; r < PEPT; r++) {
        int e = ebase + r * 256 + t;
        if (e < N_EDGES) {
            int d = ei[N_EDGES + e];
            int s = ei[e];
            int b = d >> 9;
            bk[r] = b;
            pk[r] = ((d & 511) << 17) | s;
            atomicAdd(&lcnt[b], 1);
        } else bk[r] = -1;
    }
    __syncthreads();
    for (int i = t; i < NB; i += 256) gbase[i] = atomicAdd(&gcnt[i], lcnt[i]);
    __syncthreads();
#pragma unroll
    for (int r = 0; r < PEPT; r++) {
        if (bk[r] >= 0) {
            int b = bk[r];
            int pos = gbase[b] + atomicAdd(&lcur[b], 1);
            bucketed[b * BCAP + pos] = pk[r];
        }
    }
}

__global__ __launch_bounds__(256) void k_bscan(const int* __restrict__ gcnt,
                                               int* __restrict__ base)
{
    __shared__ int s[256];
    int t = threadIdx.x;
    int v = (t < NB) ? gcnt[t] : 0;
    s[t] = v;
    __syncthreads();
#pragma unroll
    for (int off = 1; off < 256; off <<= 1) {
        int u = (t >= off) ? s[t - off] : 0;
        __syncthreads();
        s[t] += u;
        __syncthreads();
    }
    base[t] = s[t] - v;
}

// one block per bucket: local CSR in LDS + degree counting-sort -> perm
__global__ __launch_bounds__(512) void k_place(const int* __restrict__ bucketed,
                                               const int* __restrict__ gcnt,
                                               const int* __restrict__ base,
                                               int* __restrict__ csr,
                                               int* __restrict__ starts,
                                               int* __restrict__ cnt,
                                               int* __restrict__ perm)
{
    __shared__ int scnt[512], sexc[512], scur[512], dbin[64];
    int b = blockIdx.x, t = threadIdx.x;
    int ecnt = gcnt[b];
    int ebase = base[b];
    const int* bp = bucketed + b * BCAP;

    scnt[t] = 0; scur[t] = 0;
    __syncthreads();
    for (int e = t; e < ecnt; e += 512) atomicAdd(&scnt[bp[e] >> 17], 1);
    __syncthreads();
    int v = scnt[t];
    sexc[t] = v;
    __syncthreads();
#pragma unroll
    for (int off = 1; off < 512; off <<= 1) {
        int u = (t >= off) ? sexc[t - off] : 0;
        __syncthreads();
        sexc[t] += u;
        __syncthreads();
    }
    int excl = sexc[t] - v;
    __syncthreads();
    sexc[t] = excl;
    __syncthreads();

    int node = b * 512 + t;
    if (node < N_NODES) { starts[node] = ebase + excl; cnt[node] = v; }

    for (int e = t; e < ecnt; e += 512) {
        int p = bp[e];
        int ld = p >> 17;
        int pos = ebase + sexc[ld] + atomicAdd(&scur[ld], 1);
        csr[pos] = p & 0x1FFFF;
    }

    // ---- degree counting-sort of this bucket's nodes -> perm ----
    __syncthreads();
    if (t < 64) dbin[t] = 0;
    __syncthreads();
    int nvalid = N_NODES - b * 512;
    if (nvalid > 512) nvalid = 512;
    int mybin = (t < nvalid) ? (v < 63 ? v : 63) : -1;
    if (mybin >= 0) atomicAdd(&dbin[mybin], 1);
    __syncthreads();
    if (t == 0) {
        int acc = 0;
        for (int i = 0; i < 64; i++) { int c = dbin[i]; dbin[i] = acc; acc += c; }
    }
    __syncthreads();
    if (mybin >= 0) {
        int pos = atomicAdd(&dbin[mybin], 1);
        perm[b * 512 + pos] = node;
    }
}

// ======================= Layer 1: ResGated(1 -> 32), fused gather =======================
__global__ __launch_bounds__(256) void k_gath1(
    const float* __restrict__ x, const int* __restrict__ csr_src,
    const int* __restrict__ starts, const int* __restrict__ cnt,
    const int* __restrict__ perm,
    const float* __restrict__ Wk, const float* __restrict__ bk,
    const float* __restrict__ Wq, const float* __restrict__ bq,
    const float* __restrict__ Wv, const float* __restrict__ bv,
    const float* __restrict__ Wskip, const float* __restrict__ b,
    float* __restrict__ h1)
{
    int tid = blockIdx.x * 256 + threadIdx.x;
    if (tid >= N_NODES * 8) return;
    int i = perm[tid >> 3], l = tid & 7;

    float xd = x[i];
    float4 wk = ((const float4*)Wk)[l], bk4 = ((const float4*)bk)[l];
    float4 wq = ((const float4*)Wq)[l], bq4 = ((const float4*)bq)[l];
    float4 wv = ((const float4*)Wv)[l], bv4 = ((const float4*)bv)[l];
    float4 kk = make_float4(fmaf(xd, wk.x, bk4.x), fmaf(xd, wk.y, bk4.y),
                            fmaf(xd, wk.z, bk4.z), fmaf(xd, wk.w, bk4.w));

    int base = starts[i], deg = cnt[i];
    float4 a0 = make_float4(0.f, 0.f, 0.f, 0.f);
    float4 a1 = make_float4(0.f, 0.f, 0.f, 0.f);
    int e = 0;
    for (; e + 1 < deg; e += 2) {
        int s0 = csr_src[base + e];
        int s1 = csr_src[base + e + 1];
        float x0 = x[s0], x1 = x[s1];
        a0.x += sigm(kk.x + fmaf(x0, wq.x, bq4.x)) * fmaf(x0, wv.x, bv4.x);
        a0.y += sigm(kk.y + fmaf(x0, wq.y, bq4.y)) * fmaf(x0, wv.y, bv4.y);
        a0.z += sigm(kk.z + fmaf(x0, wq.z, bq4.z)) * fmaf(x0, wv.z, bv4.z);
        a0.w += sigm(kk.w + fmaf(x0, wq.w, bq4.w)) * fmaf(x0, wv.w, bv4.w);
        a1.x += sigm(kk.x + fmaf(x1, wq.x, bq4.x)) * fmaf(x1, wv.x, bv4.x);
        a1.y += sigm(kk.y + fmaf(x1, wq.y, bq4.y)) * fmaf(x1, wv.y, bv4.y);
        a1.z += sigm(kk.z + fmaf(x1, wq.z, bq4.z)) * fmaf(x1, wv.z, bv4.z);
        a1.w += sigm(kk.w + fmaf(x1, wq.w, bq4.w)) * fmaf(x1, wv.w, bv4.w);
    }
    if (e < deg) {
        int s0 = csr_src[base + e];
        float x0 = x[s0];
        a0.x += sigm(kk.x + fmaf(x0, wq.x, bq4.x)) * fmaf(x0, wv.x, bv4.x);
        a0.y += sigm(kk.y + fmaf(x0, wq.y, bq4.y)) * fmaf(x0, wv.y, bv4.y);
        a0.z += sigm(kk.z + fmaf(x0, wq.z, bq4.z)) * fmaf(x0, wv.z, bv4.z);
        a0.w += sigm(kk.w + fmaf(x0, wq.w, bq4.w)) * fmaf(x0, wv.w, bv4.w);
    }
    float4 ws4 = ((const float4*)Wskip)[l];
    float4 bb4 = ((const float4*)b)[l];
    float4 o = make_float4(a0.x + a1.x + fmaf(xd, ws4.x, bb4.x),
                           a0.y + a1.y + fmaf(xd, ws4.y, bb4.y),
                           a0.z + a1.z + fmaf(xd, ws4.z, bb4.z),
                           a0.w + a1.w + fmaf(xd, ws4.w, bb4.w));
    ((float4*)(h1 + (size_t)i * 32))[l] = o;
}

__device__ __forceinline__ float4 dot4(const float* __restrict__ h,
                                       const float* __restrict__ Wcol, int stride)
{
    float4 a = make_float4(0.f, 0.f, 0.f, 0.f);
#pragma unroll
    for (int k = 0; k < 32; k++) {
        float4 w = *(const float4*)(Wcol + k * stride);
        float hk = h[k];
        a.x = fmaf(hk, w.x, a.x);
        a.y = fmaf(hk, w.y, a.y);
        a.z = fmaf(hk, w.z, a.z);
        a.w = fmaf(hk, w.w, a.w);
    }
    return a;
}

// ======================= xl = bf16(relu(h1) @ Wlin) =======================
__global__ __launch_bounds__(256) void k_xl(
    const float* __restrict__ h1, const float* __restrict__ Wlin,
    u16* __restrict__ xlb)
{
    __shared__ float sWlin[1024];
    int t = threadIdx.x;
    for (int idx = t; idx < 1024; idx += 256) sWlin[idx] = Wlin[idx];
    __syncthreads();

    int tid = blockIdx.x * 256 + t;
    if (tid >= N_NODES * 8) return;
    int i = tid >> 3, l = tid & 7;

    float h[32];
    const float4* hp = (const float4*)(h1 + (size_t)i * 32);
#pragma unroll
    for (int j = 0; j < 8; j++) {
        float4 v = hp[j];
        h[4 * j + 0] = fmaxf(v.x, 0.f);
        h[4 * j + 1] = fmaxf(v.y, 0.f);
        h[4 * j + 2] = fmaxf(v.z, 0.f);
        h[4 * j + 3] = fmaxf(v.w, 0.f);
    }
    float4 xo = dot4(h, sWlin + l * 4, 32);
    ushort4 xp;
    xp.x = f2bf(xo.x); xp.y = f2bf(xo.y); xp.z = f2bf(xo.z); xp.w = f2bf(xo.w);
    ((ushort4*)xlb)[(size_t)i * 8 + l] = xp;
}

// ======================= Layer 2: fused FiLM gather =======================
// per node: beta/gamma/skip from own h1 row (LDS dots), then mean-gather of msgs
__global__ __launch_bounds__(256) void k_gath2f(
    const int* __restrict__ csr_src, const int* __restrict__ starts,
    const int* __restrict__ cnt, const int* __restrict__ perm,
    const float* __restrict__ h1, const u16* __restrict__ xlb,
    const float* __restrict__ Wfilm, const float* __restrict__ bfilm,
    const float* __restrict__ Wls, const float* __restrict__ Wfs,
    float* __restrict__ h2)
{
    __shared__ float sWfilm[2048], sWls[1024], sWfs[2048];
    int t = threadIdx.x;
    for (int idx = t; idx < 2048; idx += 256) sWfilm[idx] = Wfilm[idx];
    for (int idx = t; idx < 1024; idx += 256) sWls[idx] = Wls[idx];
    for (int idx = t; idx < 2048; idx += 256) sWfs[idx] = Wfs[idx];
    __syncthreads();

    int tid = blockIdx.x * 256 + t;
    if (tid >= N_NODES * 8) return;
    int i = perm[tid >> 3], l = tid & 7;

    float h[32];
    const float4* hp = (const float4*)(h1 + (size_t)i * 32);
#pragma unroll
    for (int j = 0; j < 8; j++) {
        float4 v = hp[j];
        h[4 * j + 0] = fmaxf(v.x, 0.f);
        h[4 * j + 1] = fmaxf(v.y, 0.f);
        h[4 * j + 2] = fmaxf(v.z, 0.f);
        h[4 * j + 3] = fmaxf(v.w, 0.f);
    }

    // skip path: relu(gamma_s * (h@Wls) + beta_s)
    float4 bs = dot4(h, sWfs + l * 4, 64);
    float4 gs = dot4(h, sWfs + 32 + l * 4, 64);
    float4 ls = dot4(h, sWls + l * 4, 32);
    float4 sk = make_float4(fmaxf(fmaf(gs.x, ls.x, bs.x), 0.f),
                            fmaxf(fmaf(gs.y, ls.y, bs.y), 0.f),
                            fmaxf(fmaf(gs.z, ls.z, bs.z), 0.f),
                            fmaxf(fmaf(gs.w, ls.w, bs.w), 0.f));

    // message modulation: beta = cols l*4.., gamma = cols 32+l*4..
    float4 bf = ((const float4*)bfilm)[l];
    float4 gf = ((const float4*)bfilm)[8 + l];
    float4 be = dot4(h, sWfilm + l * 4, 64);
    float4 ga = dot4(h, sWfilm + 32 + l * 4, 64);
    be.x += bf.x; be.y += bf.y; be.z += bf.z; be.w += bf.w;
    ga.x += gf.x; ga.y += gf.y; ga.z += gf.z; ga.w += gf.w;

    int base = starts[i], deg = cnt[i];
    float4 a0 = make_float4(0.f, 0.f, 0.f, 0.f);
    float4 a1 = make_float4(0.f, 0.f, 0.f, 0.f);
    int e = 0;
    for (; e + 1 < deg; e += 2) {
        int s0 = csr_src[base + e];
        int s1 = csr_src[base + e + 1];
        ushort4 u = ((const ushort4*)xlb)[(size_t)s0 * 8 + l];
        ushort4 w = ((const ushort4*)xlb)[(size_t)s1 * 8 + l];
        a0.x += fmaxf(fmaf(ga.x, bf2f(u.x), be.x), 0.f);
        a0.y += fmaxf(fmaf(ga.y, bf2f(u.y), be.y), 0.f);
        a0.z += fmaxf(fmaf(ga.z, bf2f(u.z), be.z), 0.f);
        a0.w += fmaxf(fmaf(ga.w, bf2f(u.w), be.w), 0.f);
        a1.x += fmaxf(fmaf(ga.x, bf2f(w.x), be.x), 0.f);
        a1.y += fmaxf(fmaf(ga.y, bf2f(w.y), be.y), 0.f);
        a1.z += fmaxf(fmaf(ga.z, bf2f(w.z), be.z), 0.f);
        a1.w += fmaxf(fmaf(ga.w, bf2f(w.w), be.w), 0.f);
    }
    if (e < deg) {
        int s0 = csr_src[base + e];
        ushort4 u = ((const ushort4*)xlb)[(size_t)s0 * 8 + l];
        a0.x += fmaxf(fmaf(ga.x, bf2f(u.x), be.x), 0.f);
        a0.y += fmaxf(fmaf(ga.y, bf2f(u.y), be.y), 0.f);
        a0.z += fmaxf(fmaf(ga.z, bf2f(u.z), be.z), 0.f);
        a0.w += fmaxf(fmaf(ga.w, bf2f(u.w), be.w), 0.f);
    }
    float inv = 1.0f / fmaxf((float)deg, 1.0f);
    float4 o = make_float4(fmaxf(fmaf(a0.x + a1.x, inv, sk.x), 0.f),
                           fmaxf(fmaf(a0.y + a1.y, inv, sk.y), 0.f),
                           fmaxf(fmaf(a0.z + a1.z, inv, sk.z), 0.f),
                           fmaxf(fmaf(a0.w + a1.w, inv, sk.w), 0.f));
    ((float4*)(h2 + (size_t)i * 32))[l] = o;
}

// ======================= qv = bf16(h2 @ Wq + bq | h2 @ Wv + bv) =======================
__global__ __launch_bounds__(256) void k_qv(
    const float* __restrict__ h2,
    const float* __restrict__ Wq, const float* __restrict__ bq,
    const float* __restrict__ Wv, const float* __restrict__ bv,
    u16* __restrict__ qvb)
{
    __shared__ float sWq[1024], sWv[1024];
    int t = threadIdx.x;
    for (int idx = t; idx < 1024; idx += 256) { sWq[idx] = Wq[idx]; sWv[idx] = Wv[idx]; }
    __syncthreads();

    int tid = blockIdx.x * 256 + t;
    if (tid >= N_NODES * 8) return;
    int i = tid >> 3, l = tid & 7;

    float h[32];
    const float4* hp = (const float4*)(h2 + (size_t)i * 32);
#pragma unroll
    for (int j = 0; j < 8; j++) {
        float4 v = hp[j];
        h[4 * j + 0] = v.x; h[4 * j + 1] = v.y;
        h[4 * j + 2] = v.z; h[4 * j + 3] = v.w;
    }
    float4 bq4 = ((const float4*)bq)[l];
    float4 bv4 = ((const float4*)bv)[l];
    float4 qq = dot4(h, sWq + l * 4, 32);
    qq.x += bq4.x; qq.y += bq4.y; qq.z += bq4.z; qq.w += bq4.w;
    float4 vv = dot4(h, sWv + l * 4, 32);
    vv.x += bv4.x; vv.y += bv4.y; vv.z += bv4.z; vv.w += bv4.w;

    uint4 pk;
    pk.x = (u32)f2bf(qq.x) | ((u32)f2bf(qq.y) << 16);
    pk.y = (u32)f2bf(qq.z) | ((u32)f2bf(qq.w) << 16);
    pk.z = (u32)f2bf(vv.x) | ((u32)f2bf(vv.y) << 16);
    pk.w = (u32)f2bf(vv.z) | ((u32)f2bf(vv.w) << 16);
    ((uint4*)qvb)[(size_t)i * 8 + l] = pk;
}

// ======================= Layer 3: fused ResGated gather =======================
// per node: k3 and skip-init from own h2 row (LDS dots), then gather
__global__ __launch_bounds__(256) void k_gath3f(
    const int* __restrict__ csr_src, const int* __restrict__ starts,
    const int* __restrict__ cnt, const int* __restrict__ perm,
    const float* __restrict__ h2, const u16* __restrict__ qvb,
    const float* __restrict__ Wk, const float* __restrict__ bk,
    const float* __restrict__ Wskip, const float* __restrict__ b,
    float* __restrict__ h3)
{
    __shared__ float sWk[1024], sWs[1024];
    int t = threadIdx.x;
    for (int idx = t; idx < 1024; idx += 256) { sWk[idx] = Wk[idx]; sWs[idx] = Wskip[idx]; }
    __syncthreads();

    int tid = blockIdx.x * 256 + t;
    if (tid >= N_NODES * 8) return;
    int i = perm[tid >> 3], l = tid & 7;

    float h[32];
    const float4* hp = (const float4*)(h2 + (size_t)i * 32);
#pragma unroll
    for (int j = 0; j < 8; j++) {
        float4 v = hp[j];
        h[4 * j + 0] = v.x; h[4 * j + 1] = v.y;
        h[4 * j + 2] = v.z; h[4 * j + 3] = v.w;
    }
    float4 bk4 = ((const float4*)bk)[l];
    float4 bb4 = ((const float4*)b)[l];
    float4 kk = dot4(h, sWk + l * 4, 32);
    kk.x += bk4.x; kk.y += bk4.y; kk.z += bk4.z; kk.w += bk4.w;
    float4 ss = dot4(h, sWs + l * 4, 32);
    ss.x += bb4.x; ss.y += bb4.y; ss.z += bb4.z; ss.w += bb4.w;

    int base = starts[i], deg = cnt[i];
    float4 a0 = make_float4(0.f, 0.f, 0.f, 0.f);
    float4 a1 = make_float4(0.f, 0.f, 0.f, 0.f);
    int e = 0;
    for (; e + 1 < deg; e += 2) {
        int s0 = csr_src[base + e];
        int s1 = csr_src[base + e + 1];
        uint4 p0 = ((const uint4*)qvb)[(size_t)s0 * 8 + l];
        uint4 p1 = ((const uint4*)qvb)[(size_t)s1 * 8 + l];
        a0.x += sigm(kk.x + bf2f((u16)p0.x)) * bf2f((u16)p0.z);
        a0.y += sigm(kk.y + bf2f((u16)(p0.x >> 16))) * bf2f((u16)(p0.z >> 16));
        a0.z += sigm(kk.z + bf2f((u16)p0.y)) * bf2f((u16)p0.w);
        a0.w += sigm(kk.w + bf2f((u16)(p0.y >> 16))) * bf2f((u16)(p0.w >> 16));
        a1.x += sigm(kk.x + bf2f((u16)p1.x)) * bf2f((u16)p1.z);
        a1.y += sigm(kk.y + bf2f((u16)(p1.x >> 16))) * bf2f((u16)(p1.z >> 16));
        a1.z += sigm(kk.z + bf2f((u16)p1.y)) * bf2f((u16)p1.w);
        a1.w += sigm(kk.w + bf2f((u16)(p1.y >> 16))) * bf2f((u16)(p1.w >> 16));
    }
    if (e < deg) {
        int s0 = csr_src[base + e];
        uint4 p0 = ((const uint4*)qvb)[(size_t)s0 * 8 + l];
        a0.x += sigm(kk.x + bf2f((u16)p0.x)) * bf2f((u16)p0.z);
        a0.y += sigm(kk.y + bf2f((u16)(p0.x >> 16))) * bf2f((u16)(p0.z >> 16));
        a0.z += sigm(kk.z + bf2f((u16)p0.y)) * bf2f((u16)p0.w);
        a0.w += sigm(kk.w + bf2f((u16)(p0.y >> 16))) * bf2f((u16)(p0.w >> 16));
    }
    float4 o = make_float4(ss.x + a0.x + a1.x, ss.y + a0.y + a1.y,
                           ss.z + a0.z + a1.z, ss.w + a0.w + a1.w);
    ((float4*)(h3 + (size_t)i * 32))[l] = o;
}

// ======================= pool =======================
__global__ __launch_bounds__(256) void k_gstart(const int* __restrict__ batch,
                                                int* __restrict__ gstart)
{
    int g = blockIdx.x * 256 + threadIdx.x;
    if (g > N_GRAPH) return;
    int lo = 0, hi = N_NODES;
    while (lo < hi) {
        int mid = (lo + hi) >> 1;
        if (batch[mid] < g) lo = mid + 1; else hi = mid;
    }
    gstart[g] = lo;
}

__global__ __launch_bounds__(256) void k_pool(
    const float* __restrict__ h3, const int* __restrict__ gstart,
    float* __restrict__ gmean)
{
    int tid = blockIdx.x * 256 + threadIdx.x;
    int g = tid >> 6;
    if (g >= N_GRAPH) return;
    int lane = tid & 63;
    int sub = lane >> 3, fg = lane & 7;
    int gs = gstart[g], ge = gstart[g + 1];

    float4 a = make_float4(0.f, 0.f, 0.f, 0.f);
    for (int j = gs + sub; j < ge; j += 8) {
        float4 v = ((const float4*)(h3 + (size_t)j * 32))[fg];
        a.x += v.x; a.y += v.y; a.z += v.z; a.w += v.w;
    }
#pragma unroll
    for (int off = 8; off < 64; off <<= 1) {
        a.x += __shfl_xor(a.x, off);
        a.y += __shfl_xor(a.y, off);
        a.z += __shfl_xor(a.z, off);
        a.w += __shfl_xor(a.w, off);
    }
    if (sub == 0) {
        float inv = 1.0f / fmaxf((float)(ge - gs), 1.0f);
        a.x *= inv; a.y *= inv; a.z *= inv; a.w *= inv;
        ((float4*)(gmean + (size_t)g * 32))[fg] = a;
    }
}

__global__ __launch_bounds__(256) void k_final(
    const float* __restrict__ gmean,
    const float* __restrict__ linW, const float* __restrict__ linb,
    float* __restrict__ out)
{
    int tid = blockIdx.x * 256 + threadIdx.x;
    if (tid >= N_GRAPH * 10) return;
    int g = tid / 10, c = tid % 10;
    const float* gr = gmean + (size_t)g * 32;
    float a = 0.f;
#pragma unroll
    for (int k = 0; k < 32; k++) a = fmaf(gr[k], linW[k * 10 + c], a);
    out[tid] = a + linb[c];
}

extern "C" void kernel_launch(void* const* d_in, const int* in_sizes, int n_in,
                              void* d_out, int out_size, void* d_ws, size_t ws_size,
                              hipStream_t stream)
{
    const float* x      = (const float*)d_in[0];
    const int*   ei     = (const int*)d_in[1];
    const int*   batch  = (const int*)d_in[2];
    const float* c1_Wk   = (const float*)d_in[4];
    const float* c1_bk   = (const float*)d_in[5];
    const float* c1_Wq   = (const float*)d_in[6];
    const float* c1_bq   = (const float*)d_in[7];
    const float* c1_Wv   = (const float*)d_in[8];
    const float* c1_bv   = (const float*)d_in[9];
    const float* c1_Wsk  = (const float*)d_in[10];
    const float* c1_b    = (const float*)d_in[11];
    const float* c2_Wlin = (const float*)d_in[12];
    const float* c2_Wfilm= (const float*)d_in[13];
    const float* c2_bfilm= (const float*)d_in[14];
    const float* c2_Wls  = (const float*)d_in[15];
    const float* c2_Wfs  = (const float*)d_in[16];
    const float* c3_Wk   = (const float*)d_in[17];
    const float* c3_bk   = (const float*)d_in[18];
    const float* c3_Wq   = (const float*)d_in[19];
    const float* c3_bq   = (const float*)d_in[20];
    const float* c3_Wv   = (const float*)d_in[21];
    const float* c3_bv   = (const float*)d_in[22];
    const float* c3_Wsk  = (const float*)d_in[23];
    const float* c3_b    = (const float*)d_in[24];
    const float* lin_W   = (const float*)d_in[25];
    const float* lin_b   = (const float*)d_in[26];
    float* out = (float*)d_out;

    const size_t N = N_NODES;

    // ---- workspace layout ----
    int* gcnt    = (int*)d_ws;              // 256 (zeroed)
    int* bbase   = gcnt + 256;              // 256
    int* igstart = bbase + 256;             // 1056
    int* bucketed= igstart + 1056;          // NB*BCAP
    int* icsr    = bucketed + NB * BCAP;    // E
    int* istarts = icsr + N_EDGES;          // N
    int* icnt    = istarts + N;             // N
    int* iperm   = icnt + N;                // N
    float* h1    = (float*)(iperm + N);     // N*32 (reused as h3)
    float* h2    = h1 + N * 32;             // N*32
    u16*   xlb   = (u16*)(h2 + N * 32);     // N*32 bf16
    u16*   qvb   = xlb + N * 32;            // N*64 bf16 (q|v packed)
    float* gmean = (float*)(qvb + N * 64);  // G*32

    hipMemsetAsync(gcnt, 0, 256 * sizeof(int), stream);

    const int TB = 256;
    int gPart  = (N_EDGES + 256 * PEPT - 1) / (256 * PEPT);  // 391
    int gNode8 = (N_NODES * 8 + TB - 1) / TB;                // 3125
    int gFin   = (N_GRAPH * 10 + TB - 1) / TB;               // 40

    // CSR build + degree-sorted perm
    k_partition<<<gPart, TB, 0, stream>>>(ei, gcnt, bucketed);
    k_bscan<<<1, 256, 0, stream>>>(gcnt, bbase);
    k_place<<<NB, 512, 0, stream>>>(bucketed, gcnt, bbase, icsr, istarts, icnt, iperm);
    k_gstart<<<5, TB, 0, stream>>>(batch, igstart);

    // Layer 1 (fused gather)
    k_gath1<<<gNode8, TB, 0, stream>>>(x, icsr, istarts, icnt, iperm,
                                       c1_Wk, c1_bk, c1_Wq, c1_bq,
                                       c1_Wv, c1_bv, c1_Wsk, c1_b, h1);
    // Layer 2 (FiLM): xl precompute + fused gather
    k_xl<<<gNode8, TB, 0, stream>>>(h1, c2_Wlin, xlb);
    k_gath2f<<<gNode8, TB, 0, stream>>>(icsr, istarts, icnt, iperm, h1, xlb,
                                        c2_Wfilm, c2_bfilm, c2_Wls, c2_Wfs, h2);
    // Layer 3 (ResGated): qv precompute + fused gather
    k_qv<<<gNode8, TB, 0, stream>>>(h2, c3_Wq, c3_bq, c3_Wv, c3_bv, qvb);
    float* h3 = h1;  // reuse
    k_gath3f<<<gNode8, TB, 0, stream>>>(icsr, istarts, icnt, iperm, h2, qvb,
                                        c3_Wk, c3_bk, c3_Wsk, c3_b, h3);
    // Pool + classifier
    k_pool<<<256, TB, 0, stream>>>(h3, igstart, gmean);
    k_final<<<gFin, TB, 0, stream>>>(gmean, lin_W, lin_b, out);
}

// Round 6
// 351.887 us; speedup vs baseline: 1.4504x; 1.4504x over previous
//
#include <hip/hip_runtime.h>

#define N_NODES 100000
#define N_EDGES 1600000
#define N_GRAPH 1024
#define NB      196      // buckets of 512 nodes
#define BCAP    10240    // bucket capacity (mean 8192, ~22 sigma slack)
#define PEPT    16       // edges per thread in partition

typedef unsigned short u16;
typedef unsigned int   u32;

__device__ __forceinline__ float sigm(float z) { return 1.0f / (1.0f + __expf(-z)); }
__device__ __forceinline__ u16 f2bf(float f) {
    u32 u = __float_as_uint(f);
    u += 0x7FFFu + ((u >> 16) & 1u);
    return (u16)(u >> 16);
}
__device__ __forceinline__ float bf2f(u16 h) { return __uint_as_float(((u32)h) << 16); }

// ======================= CSR build: bucket partition =======================
__global__ __launch_bounds__(256) void k_partition(const int* __restrict__ ei,
                                                   int* __restrict__ gcnt,
                                                   int* __restrict__ bucketed)
{
    __shared__ int lcnt[NB], gbase[NB], lcur[NB];
    int t = threadIdx.x;
    for (int i = t; i < NB; i += 256) { lcnt[i] = 0; lcur[i] = 0; }
    __syncthreads();

    int ebase = blockIdx.x * (256 * PEPT);
    int pk[PEPT], bk[PEPT];
#pragma unroll
    for (int r = 0; r < PEPT; r++) {
        int e = ebase + r * 256 + t;
        if (e < N_EDGES) {
            int d = ei[N_EDGES + e];
            int s = ei[e];
            int b = d >> 9;
            bk[r] = b;
            pk[r] = ((d & 511) << 17) | s;
            atomicAdd(&lcnt[b], 1);
        } else bk[r] = -1;
    }
    __syncthreads();
    for (int i = t; i < NB; i += 256) gbase[i] = atomicAdd(&gcnt[i], lcnt[i]);
    __syncthreads();
#pragma unroll
    for (int r = 0; r < PEPT; r++) {
        if (bk[r] >= 0) {
            int b = bk[r];
            int pos = gbase[b] + atomicAdd(&lcur[b], 1);
            bucketed[b * BCAP + pos] = pk[r];
        }
    }
}

__global__ __launch_bounds__(256) void k_bscan(const int* __restrict__ gcnt,
                                               int* __restrict__ base)
{
    __shared__ int s[256];
    int t = threadIdx.x;
    int v = (t < NB) ? gcnt[t] : 0;
    s[t] = v;
    __syncthreads();
#pragma unroll
    for (int off = 1; off < 256; off <<= 1) {
        int u = (t >= off) ? s[t - off] : 0;
        __syncthreads();
        s[t] += u;
        __syncthreads();
    }
    base[t] = s[t] - v;
}

// one block per bucket: local CSR in LDS + degree counting-sort -> perm
__global__ __launch_bounds__(512) void k_place(const int* __restrict__ bucketed,
                                               const int* __restrict__ gcnt,
                                               const int* __restrict__ base,
                                               int* __restrict__ csr,
                                               int* __restrict__ starts,
                                               int* __restrict__ cnt,
                                               int* __restrict__ perm)
{
    __shared__ int scnt[512], sexc[512], scur[512], dbin[64];
    int b = blockIdx.x, t = threadIdx.x;
    int ecnt = gcnt[b];
    int ebase = base[b];
    const int* bp = bucketed + b * BCAP;

    scnt[t] = 0; scur[t] = 0;
    __syncthreads();
    for (int e = t; e < ecnt; e += 512) atomicAdd(&scnt[bp[e] >> 17], 1);
    __syncthreads();
    int v = scnt[t];
    sexc[t] = v;
    __syncthreads();
#pragma unroll
    for (int off = 1; off < 512; off <<= 1) {
        int u = (t >= off) ? sexc[t - off] : 0;
        __syncthreads();
        sexc[t] += u;
        __syncthreads();
    }
    int excl = sexc[t] - v;
    __syncthreads();
    sexc[t] = excl;
    __syncthreads();

    int node = b * 512 + t;
    if (node < N_NODES) { starts[node] = ebase + excl; cnt[node] = v; }

    for (int e = t; e < ecnt; e += 512) {
        int p = bp[e];
        int ld = p >> 17;
        int pos = ebase + sexc[ld] + atomicAdd(&scur[ld], 1);
        csr[pos] = p & 0x1FFFF;
    }

    // degree counting-sort of this bucket's nodes -> perm (equal-degree waves)
    __syncthreads();
    if (t < 64) dbin[t] = 0;
    __syncthreads();
    int nvalid = N_NODES - b * 512;
    if (nvalid > 512) nvalid = 512;
    int mybin = (t < nvalid) ? (v < 63 ? v : 63) : -1;
    if (mybin >= 0) atomicAdd(&dbin[mybin], 1);
    __syncthreads();
    if (t == 0) {
        int acc = 0;
        for (int i = 0; i < 64; i++) { int c = dbin[i]; dbin[i] = acc; acc += c; }
    }
    __syncthreads();
    if (mybin >= 0) {
        int pos = atomicAdd(&dbin[mybin], 1);
        perm[b * 512 + pos] = node;
    }
}

// ======================= Layer 1: ResGated(1 -> 32), fused gather =======================
__global__ __launch_bounds__(256) void k_gath1(
    const float* __restrict__ x, const int* __restrict__ csr_src,
    const int* __restrict__ starts, const int* __restrict__ cnt,
    const int* __restrict__ perm,
    const float* __restrict__ Wk, const float* __restrict__ bk,
    const float* __restrict__ Wq, const float* __restrict__ bq,
    const float* __restrict__ Wv, const float* __restrict__ bv,
    const float* __restrict__ Wskip, const float* __restrict__ b,
    float* __restrict__ h1)
{
    int tid = blockIdx.x * 256 + threadIdx.x;
    if (tid >= N_NODES * 8) return;
    int i = perm[tid >> 3], l = tid & 7;

    float xd = x[i];
    float4 wk = ((const float4*)Wk)[l], bk4 = ((const float4*)bk)[l];
    float4 wq = ((const float4*)Wq)[l], bq4 = ((const float4*)bq)[l];
    float4 wv = ((const float4*)Wv)[l], bv4 = ((const float4*)bv)[l];
    float4 kk = make_float4(fmaf(xd, wk.x, bk4.x), fmaf(xd, wk.y, bk4.y),
                            fmaf(xd, wk.z, bk4.z), fmaf(xd, wk.w, bk4.w));

    int base = starts[i], deg = cnt[i];
    float4 a0 = make_float4(0.f, 0.f, 0.f, 0.f);
    float4 a1 = make_float4(0.f, 0.f, 0.f, 0.f);
    int e = 0;
    for (; e + 1 < deg; e += 2) {
        int s0 = csr_src[base + e];
        int s1 = csr_src[base + e + 1];
        float x0 = x[s0], x1 = x[s1];
        a0.x += sigm(kk.x + fmaf(x0, wq.x, bq4.x)) * fmaf(x0, wv.x, bv4.x);
        a0.y += sigm(kk.y + fmaf(x0, wq.y, bq4.y)) * fmaf(x0, wv.y, bv4.y);
        a0.z += sigm(kk.z + fmaf(x0, wq.z, bq4.z)) * fmaf(x0, wv.z, bv4.z);
        a0.w += sigm(kk.w + fmaf(x0, wq.w, bq4.w)) * fmaf(x0, wv.w, bv4.w);
        a1.x += sigm(kk.x + fmaf(x1, wq.x, bq4.x)) * fmaf(x1, wv.x, bv4.x);
        a1.y += sigm(kk.y + fmaf(x1, wq.y, bq4.y)) * fmaf(x1, wv.y, bv4.y);
        a1.z += sigm(kk.z + fmaf(x1, wq.z, bq4.z)) * fmaf(x1, wv.z, bv4.z);
        a1.w += sigm(kk.w + fmaf(x1, wq.w, bq4.w)) * fmaf(x1, wv.w, bv4.w);
    }
    if (e < deg) {
        int s0 = csr_src[base + e];
        float x0 = x[s0];
        a0.x += sigm(kk.x + fmaf(x0, wq.x, bq4.x)) * fmaf(x0, wv.x, bv4.x);
        a0.y += sigm(kk.y + fmaf(x0, wq.y, bq4.y)) * fmaf(x0, wv.y, bv4.y);
        a0.z += sigm(kk.z + fmaf(x0, wq.z, bq4.z)) * fmaf(x0, wv.z, bv4.z);
        a0.w += sigm(kk.w + fmaf(x0, wq.w, bq4.w)) * fmaf(x0, wv.w, bv4.w);
    }
    float4 ws4 = ((const float4*)Wskip)[l];
    float4 bb4 = ((const float4*)b)[l];
    float4 o = make_float4(a0.x + a1.x + fmaf(xd, ws4.x, bb4.x),
                           a0.y + a1.y + fmaf(xd, ws4.y, bb4.y),
                           a0.z + a1.z + fmaf(xd, ws4.z, bb4.z),
                           a0.w + a1.w + fmaf(xd, ws4.w, bb4.w));
    ((float4*)(h1 + (size_t)i * 32))[l] = o;
}

__device__ __forceinline__ float4 dot4(const float* __restrict__ h,
                                       const float* __restrict__ Wcol, int stride)
{
    float4 a = make_float4(0.f, 0.f, 0.f, 0.f);
#pragma unroll
    for (int k = 0; k < 32; k++) {
        float4 w = *(const float4*)(Wcol + k * stride);
        float hk = h[k];
        a.x = fmaf(hk, w.x, a.x);
        a.y = fmaf(hk, w.y, a.y);
        a.z = fmaf(hk, w.z, a.z);
        a.w = fmaf(hk, w.w, a.w);
    }
    return a;
}

// ======================= Layer 2: FiLM node-side =======================
__global__ __launch_bounds__(256) void k_node2(
    const float* __restrict__ h1,
    const float* __restrict__ Wlin, const float* __restrict__ Wfilm,
    const float* __restrict__ bfilm, const float* __restrict__ Wls,
    const float* __restrict__ Wfs,
    float* __restrict__ skip2, float* __restrict__ bg2, u16* __restrict__ xlb)
{
    __shared__ float sWlin[1024], sWfilm[2048], sWls[1024], sWfs[2048];
    int t = threadIdx.x;
    for (int idx = t; idx < 1024; idx += 256) sWlin[idx] = Wlin[idx];
    for (int idx = t; idx < 2048; idx += 256) sWfilm[idx] = Wfilm[idx];
    for (int idx = t; idx < 1024; idx += 256) sWls[idx] = Wls[idx];
    for (int idx = t; idx < 2048; idx += 256) sWfs[idx] = Wfs[idx];
    __syncthreads();

    int tid = blockIdx.x * 256 + t;
    if (tid >= N_NODES * 8) return;
    int i = tid >> 3, l = tid & 7;

    float h[32];
    const float4* hp = (const float4*)(h1 + (size_t)i * 32);
#pragma unroll
    for (int j = 0; j < 8; j++) {
        float4 v = hp[j];
        h[4 * j + 0] = fmaxf(v.x, 0.f);
        h[4 * j + 1] = fmaxf(v.y, 0.f);
        h[4 * j + 2] = fmaxf(v.z, 0.f);
        h[4 * j + 3] = fmaxf(v.w, 0.f);
    }

    float4 bs = dot4(h, sWfs + l * 4, 64);
    float4 gs = dot4(h, sWfs + 32 + l * 4, 64);
    float4 ls = dot4(h, sWls + l * 4, 32);
    float4 sk = make_float4(fmaxf(fmaf(gs.x, ls.x, bs.x), 0.f),
                            fmaxf(fmaf(gs.y, ls.y, bs.y), 0.f),
                            fmaxf(fmaf(gs.z, ls.z, bs.z), 0.f),
                            fmaxf(fmaf(gs.w, ls.w, bs.w), 0.f));
    ((float4*)(skip2 + (size_t)i * 32))[l] = sk;

    float4 bf0 = ((const float4*)bfilm)[l * 2];
    float4 bf1 = ((const float4*)bfilm)[l * 2 + 1];
    float4 f0 = dot4(h, sWfilm + l * 8, 64);
    float4 f1 = dot4(h, sWfilm + l * 8 + 4, 64);
    f0.x += bf0.x; f0.y += bf0.y; f0.z += bf0.z; f0.w += bf0.w;
    f1.x += bf1.x; f1.y += bf1.y; f1.z += bf1.z; f1.w += bf1.w;
    float4* bgp = (float4*)(bg2 + (size_t)i * 64);
    bgp[l * 2] = f0;
    bgp[l * 2 + 1] = f1;

    float4 xo = dot4(h, sWlin + l * 4, 32);
    ushort4 xp;
    xp.x = f2bf(xo.x); xp.y = f2bf(xo.y); xp.z = f2bf(xo.z); xp.w = f2bf(xo.w);
    ((ushort4*)xlb)[(size_t)i * 8 + l] = xp;
}

// FiLM gather (degree-sorted): h2 = relu(skip2 + mean relu(gamma_i*xl_s + beta_i))
__global__ __launch_bounds__(256) void k_gath2(
    const int* __restrict__ csr_src, const int* __restrict__ starts,
    const int* __restrict__ cnt, const int* __restrict__ perm,
    const float* __restrict__ bg2, const u16* __restrict__ xlb,
    const float* __restrict__ skip2, float* __restrict__ h2)
{
    int tid = blockIdx.x * 256 + threadIdx.x;
    if (tid >= N_NODES * 8) return;
    int i = perm[tid >> 3], l = tid & 7;

    float4 be = ((const float4*)(bg2 + (size_t)i * 64))[l];
    float4 ga = ((const float4*)(bg2 + (size_t)i * 64 + 32))[l];

    int base = starts[i], deg = cnt[i];
    float4 a0 = make_float4(0.f, 0.f, 0.f, 0.f);
    float4 a1 = make_float4(0.f, 0.f, 0.f, 0.f);
    int e = 0;
    for (; e + 1 < deg; e += 2) {
        int s0 = csr_src[base + e];
        int s1 = csr_src[base + e + 1];
        ushort4 u = ((const ushort4*)xlb)[(size_t)s0 * 8 + l];
        ushort4 w = ((const ushort4*)xlb)[(size_t)s1 * 8 + l];
        a0.x += fmaxf(fmaf(ga.x, bf2f(u.x), be.x), 0.f);
        a0.y += fmaxf(fmaf(ga.y, bf2f(u.y), be.y), 0.f);
        a0.z += fmaxf(fmaf(ga.z, bf2f(u.z), be.z), 0.f);
        a0.w += fmaxf(fmaf(ga.w, bf2f(u.w), be.w), 0.f);
        a1.x += fmaxf(fmaf(ga.x, bf2f(w.x), be.x), 0.f);
        a1.y += fmaxf(fmaf(ga.y, bf2f(w.y), be.y), 0.f);
        a1.z += fmaxf(fmaf(ga.z, bf2f(w.z), be.z), 0.f);
        a1.w += fmaxf(fmaf(ga.w, bf2f(w.w), be.w), 0.f);
    }
    if (e < deg) {
        int s0 = csr_src[base + e];
        ushort4 u = ((const ushort4*)xlb)[(size_t)s0 * 8 + l];
        a0.x += fmaxf(fmaf(ga.x, bf2f(u.x), be.x), 0.f);
        a0.y += fmaxf(fmaf(ga.y, bf2f(u.y), be.y), 0.f);
        a0.z += fmaxf(fmaf(ga.z, bf2f(u.z), be.z), 0.f);
        a0.w += fmaxf(fmaf(ga.w, bf2f(u.w), be.w), 0.f);
    }
    float inv = 1.0f / fmaxf((float)deg, 1.0f);
    float4 sk = ((const float4*)(skip2 + (size_t)i * 32))[l];
    float4 o = make_float4(fmaxf(fmaf(a0.x + a1.x, inv, sk.x), 0.f),
                           fmaxf(fmaf(a0.y + a1.y, inv, sk.y), 0.f),
                           fmaxf(fmaf(a0.z + a1.z, inv, sk.z), 0.f),
                           fmaxf(fmaf(a0.w + a1.w, inv, sk.w), 0.f));
    ((float4*)(h2 + (size_t)i * 32))[l] = o;
}

// ======================= Layer 3 node-side =======================
__global__ __launch_bounds__(256) void k_node3(
    const float* __restrict__ h2,
    const float* __restrict__ Wk, const float* __restrict__ bk,
    const float* __restrict__ Wq, const float* __restrict__ bq,
    const float* __restrict__ Wv, const float* __restrict__ bv,
    const float* __restrict__ Wskip, const float* __restrict__ b,
    float* __restrict__ k3, u16* __restrict__ qvb, float* __restrict__ acc3)
{
    __shared__ float sWk[1024], sWq[1024], sWv[1024], sWs[1024];
    int t = threadIdx.x;
    for (int idx = t; idx < 1024; idx += 256) {
        sWk[idx] = Wk[idx];
        sWq[idx] = Wq[idx];
        sWv[idx] = Wv[idx];
        sWs[idx] = Wskip[idx];
    }
    __syncthreads();

    int tid = blockIdx.x * 256 + t;
    if (tid >= N_NODES * 8) return;
    int i = tid >> 3, l = tid & 7;

    float h[32];
    const float4* hp = (const float4*)(h2 + (size_t)i * 32);
#pragma unroll
    for (int j = 0; j < 8; j++) {
        float4 v = hp[j];
        h[4 * j + 0] = v.x; h[4 * j + 1] = v.y;
        h[4 * j + 2] = v.z; h[4 * j + 3] = v.w;
    }

    float4 bk4 = ((const float4*)bk)[l];
    float4 bq4 = ((const float4*)bq)[l];
    float4 bv4 = ((const float4*)bv)[l];
    float4 bb4 = ((const float4*)b)[l];

    float4 kk = dot4(h, sWk + l * 4, 32);
    kk.x += bk4.x; kk.y += bk4.y; kk.z += bk4.z; kk.w += bk4.w;
    ((float4*)(k3 + (size_t)i * 32))[l] = kk;

    float4 qq = dot4(h, sWq + l * 4, 32);
    qq.x += bq4.x; qq.y += bq4.y; qq.z += bq4.z; qq.w += bq4.w;
    float4 vv = dot4(h, sWv + l * 4, 32);
    vv.x += bv4.x; vv.y += bv4.y; vv.z += bv4.z; vv.w += bv4.w;

    // node i occupies uint4 indices [i*8, i*8+8)
    uint4 pk;
    pk.x = (u32)f2bf(qq.x) | ((u32)f2bf(qq.y) << 16);
    pk.y = (u32)f2bf(qq.z) | ((u32)f2bf(qq.w) << 16);
    pk.z = (u32)f2bf(vv.x) | ((u32)f2bf(vv.y) << 16);
    pk.w = (u32)f2bf(vv.z) | ((u32)f2bf(vv.w) << 16);
    ((uint4*)qvb)[(size_t)i * 8 + l] = pk;

    float4 ss = dot4(h, sWs + l * 4, 32);
    ss.x += bb4.x; ss.y += bb4.y; ss.z += bb4.z; ss.w += bb4.w;
    ((float4*)(acc3 + (size_t)i * 32))[l] = ss;
}

// ResGated gather (degree-sorted): acc3 += sum sigm(k3_i + q_s) * v_s
__global__ __launch_bounds__(256) void k_gath3(
    const int* __restrict__ csr_src, const int* __restrict__ starts,
    const int* __restrict__ cnt, const int* __restrict__ perm,
    const float* __restrict__ k3, const u16* __restrict__ qvb,
    float* __restrict__ acc3)
{
    int tid = blockIdx.x * 256 + threadIdx.x;
    if (tid >= N_NODES * 8) return;
    int i = perm[tid >> 3], l = tid & 7;

    float4 kk = ((const float4*)(k3 + (size_t)i * 32))[l];
    int base = starts[i], deg = cnt[i];
    float4 a0 = make_float4(0.f, 0.f, 0.f, 0.f);
    float4 a1 = make_float4(0.f, 0.f, 0.f, 0.f);
    int e = 0;
    for (; e + 1 < deg; e += 2) {
        int s0 = csr_src[base + e];
        int s1 = csr_src[base + e + 1];
        uint4 p0 = ((const uint4*)qvb)[(size_t)s0 * 8 + l];
        uint4 p1 = ((const uint4*)qvb)[(size_t)s1 * 8 + l];
        a0.x += sigm(kk.x + bf2f((u16)p0.x)) * bf2f((u16)p0.z);
        a0.y += sigm(kk.y + bf2f((u16)(p0.x >> 16))) * bf2f((u16)(p0.z >> 16));
        a0.z += sigm(kk.z + bf2f((u16)p0.y)) * bf2f((u16)p0.w);
        a0.w += sigm(kk.w + bf2f((u16)(p0.y >> 16))) * bf2f((u16)(p0.w >> 16));
        a1.x += sigm(kk.x + bf2f((u16)p1.x)) * bf2f((u16)p1.z);
        a1.y += sigm(kk.y + bf2f((u16)(p1.x >> 16))) * bf2f((u16)(p1.z >> 16));
        a1.z += sigm(kk.z + bf2f((u16)p1.y)) * bf2f((u16)p1.w);
        a1.w += sigm(kk.w + bf2f((u16)(p1.y >> 16))) * bf2f((u16)(p1.w >> 16));
    }
    if (e < deg) {
        int s0 = csr_src[base + e];
        uint4 p0 = ((const uint4*)qvb)[(size_t)s0 * 8 + l];
        a0.x += sigm(kk.x + bf2f((u16)p0.x)) * bf2f((u16)p0.z);
        a0.y += sigm(kk.y + bf2f((u16)(p0.x >> 16))) * bf2f((u16)(p0.z >> 16));
        a0.z += sigm(kk.z + bf2f((u16)p0.y)) * bf2f((u16)p0.w);
        a0.w += sigm(kk.w + bf2f((u16)(p0.y >> 16))) * bf2f((u16)(p0.w >> 16));
    }
    float4* op = (float4*)(acc3 + (size_t)i * 32) + l;
    float4 cur = *op;
    cur.x += a0.x + a1.x;
    cur.y += a0.y + a1.y;
    cur.z += a0.z + a1.z;
    cur.w += a0.w + a1.w;
    *op = cur;
}

// ======================= pool =======================
__global__ __launch_bounds__(256) void k_gstart(const int* __restrict__ batch,
                                                int* __restrict__ gstart)
{
    int g = blockIdx.x * 256 + threadIdx.x;
    if (g > N_GRAPH) return;
    int lo = 0, hi = N_NODES;
    while (lo < hi) {
        int mid = (lo + hi) >> 1;
        if (batch[mid] < g) lo = mid + 1; else hi = mid;
    }
    gstart[g] = lo;
}

__global__ __launch_bounds__(256) void k_pool(
    const float* __restrict__ h3, const int* __restrict__ gstart,
    float* __restrict__ gmean)
{
    int tid = blockIdx.x * 256 + threadIdx.x;
    int g = tid >> 6;
    if (g >= N_GRAPH) return;
    int lane = tid & 63;
    int sub = lane >> 3, fg = lane & 7;
    int gs = gstart[g], ge = gstart[g + 1];

    float4 a = make_float4(0.f, 0.f, 0.f, 0.f);
    for (int j = gs + sub; j < ge; j += 8) {
        float4 v = ((const float4*)(h3 + (size_t)j * 32))[fg];
        a.x += v.x; a.y += v.y; a.z += v.z; a.w += v.w;
    }
#pragma unroll
    for (int off = 8; off < 64; off <<= 1) {
        a.x += __shfl_xor(a.x, off);
        a.y += __shfl_xor(a.y, off);
        a.z += __shfl_xor(a.z, off);
        a.w += __shfl_xor(a.w, off);
    }
    if (sub == 0) {
        float inv = 1.0f / fmaxf((float)(ge - gs), 1.0f);
        a.x *= inv; a.y *= inv; a.z *= inv; a.w *= inv;
        ((float4*)(gmean + (size_t)g * 32))[fg] = a;
    }
}

__global__ __launch_bounds__(256) void k_final(
    const float* __restrict__ gmean,
    const float* __restrict__ linW, const float* __restrict__ linb,
    float* __restrict__ out)
{
    int tid = blockIdx.x * 256 + threadIdx.x;
    if (tid >= N_GRAPH * 10) return;
    int g = tid / 10, c = tid % 10;
    const float* gr = gmean + (size_t)g * 32;
    float a = 0.f;
#pragma unroll
    for (int k = 0; k < 32; k++) a = fmaf(gr[k], linW[k * 10 + c], a);
    out[tid] = a + linb[c];
}

extern "C" void kernel_launch(void* const* d_in, const int* in_sizes, int n_in,
                              void* d_out, int out_size, void* d_ws, size_t ws_size,
                              hipStream_t stream)
{
    const float* x      = (const float*)d_in[0];
    const int*   ei     = (const int*)d_in[1];
    const int*   batch  = (const int*)d_in[2];
    const float* c1_Wk   = (const float*)d_in[4];
    const float* c1_bk   = (const float*)d_in[5];
    const float* c1_Wq   = (const float*)d_in[6];
    const float* c1_bq   = (const float*)d_in[7];
    const float* c1_Wv   = (const float*)d_in[8];
    const float* c1_bv   = (const float*)d_in[9];
    const float* c1_Wsk  = (const float*)d_in[10];
    const float* c1_b    = (const float*)d_in[11];
    const float* c2_Wlin = (const float*)d_in[12];
    const float* c2_Wfilm= (const float*)d_in[13];
    const float* c2_bfilm= (const float*)d_in[14];
    const float* c2_Wls  = (const float*)d_in[15];
    const float* c2_Wfs  = (const float*)d_in[16];
    const float* c3_Wk   = (const float*)d_in[17];
    const float* c3_bk   = (const float*)d_in[18];
    const float* c3_Wq   = (const float*)d_in[19];
    const float* c3_bq   = (const float*)d_in[20];
    const float* c3_Wv   = (const float*)d_in[21];
    const float* c3_bv   = (const float*)d_in[22];
    const float* c3_Wsk  = (const float*)d_in[23];
    const float* c3_b    = (const float*)d_in[24];
    const float* lin_W   = (const float*)d_in[25];
    const float* lin_b   = (const float*)d_in[26];
    float* out = (float*)d_out;

    const size_t N = N_NODES;

    // ---- workspace layout ----
    int* gcnt    = (int*)d_ws;              // 256 (zeroed)
    int* bbase   = gcnt + 256;              // 256
    int* igstart = bbase + 256;             // 1056
    int* bucketed= igstart + 1056;          // NB*BCAP
    int* icsr    = bucketed + NB * BCAP;    // E
    int* istarts = icsr + N_EDGES;          // N
    int* icnt    = istarts + N;             // N
    int* iperm   = icnt + N;                // N
    float* h1    = (float*)(iperm + N);     // N*32 (reused as h2)
    float* skip2 = h1 + N * 32;             // N*32 (reused as k3)
    float* bg2   = skip2 + N * 32;          // N*64 (lower half reused as qvb bf16, upper as acc3/h3)
    u16*   xlb   = (u16*)(bg2 + N * 64);    // N*32 bf16
    float* gmean = (float*)(xlb + N * 32);  // G*32

    hipMemsetAsync(gcnt, 0, 256 * sizeof(int), stream);

    const int TB = 256;
    int gPart  = (N_EDGES + 256 * PEPT - 1) / (256 * PEPT);  // 391
    int gNode8 = (N_NODES * 8 + TB - 1) / TB;                // 3125
    int gFin   = (N_GRAPH * 10 + TB - 1) / TB;               // 40

    // CSR build + degree-sorted perm
    k_partition<<<gPart, TB, 0, stream>>>(ei, gcnt, bucketed);
    k_bscan<<<1, 256, 0, stream>>>(gcnt, bbase);
    k_place<<<NB, 512, 0, stream>>>(bucketed, gcnt, bbase, icsr, istarts, icnt, iperm);
    k_gstart<<<5, TB, 0, stream>>>(batch, igstart);

    // Layer 1 (fused gather, degree-sorted)
    k_gath1<<<gNode8, TB, 0, stream>>>(x, icsr, istarts, icnt, iperm,
                                       c1_Wk, c1_bk, c1_Wq, c1_bq,
                                       c1_Wv, c1_bv, c1_Wsk, c1_b, h1);
    // Layer 2 (FiLM)
    k_node2<<<gNode8, TB, 0, stream>>>(h1, c2_Wlin, c2_Wfilm, c2_bfilm,
                                       c2_Wls, c2_Wfs, skip2, bg2, xlb);
    float* h2 = h1;
    k_gath2<<<gNode8, TB, 0, stream>>>(icsr, istarts, icnt, iperm,
                                       bg2, xlb, skip2, h2);
    // Layer 3 (ResGated)
    float* k3   = skip2;
    u16*   qvb  = (u16*)bg2;
    float* acc3 = bg2 + N * 32;
    k_node3<<<gNode8, TB, 0, stream>>>(h2, c3_Wk, c3_bk, c3_Wq, c3_bq,
                                       c3_Wv, c3_bv, c3_Wsk, c3_b,
                                       k3, qvb, acc3);
    k_gath3<<<gNode8, TB, 0, stream>>>(icsr, istarts, icnt, iperm, k3, qvb, acc3);
    // Pool + classifier
    k_pool<<<256, TB, 0, stream>>>(acc3, igstart, gmean);
    k_final<<<gFin, TB, 0, stream>>>(gmean, lin_W, lin_b, out);
}

// Round 7
// 313.350 us; speedup vs baseline: 1.6288x; 1.1230x over previous
//
#include <hip/hip_runtime.h>

#define N_NODES 100000
#define N_EDGES 1600000
#define N_GRAPH 1024
#define NB      196      // buckets of 512 nodes
#define BCAP    10240    // bucket capacity (mean 8192, ~22 sigma slack)
#define PEPT    16       // edges per thread in partition

typedef unsigned short u16;
typedef unsigned int   u32;

__device__ __forceinline__ u16 f2bf(float f) {
    u32 u = __float_as_uint(f);
    u += 0x7FFFu + ((u >> 16) & 1u);
    return (u16)(u >> 16);
}
__device__ __forceinline__ float bf2f(u16 h) { return __uint_as_float(((u32)h) << 16); }
__device__ __forceinline__ float rcpf(float x) { return __builtin_amdgcn_rcpf(x); }

// ======================= CSR build: bucket partition =======================
__global__ __launch_bounds__(256) void k_partition(const int* __restrict__ ei,
                                                   int* __restrict__ gcnt,
                                                   int* __restrict__ bucketed)
{
    __shared__ int lcnt[NB], gbase[NB], lcur[NB];
    int t = threadIdx.x;
    for (int i = t; i < NB; i += 256) { lcnt[i] = 0; lcur[i] = 0; }
    __syncthreads();

    int ebase = blockIdx.x * (256 * PEPT);
    int pk[PEPT], bk[PEPT];
#pragma unroll
    for (int r = 0; r < PEPT; r++) {
        int e = ebase + r * 256 + t;
        if (e < N_EDGES) {
            int d = ei[N_EDGES + e];
            int s = ei[e];
            int b = d >> 9;
            bk[r] = b;
            pk[r] = ((d & 511) << 17) | s;
            atomicAdd(&lcnt[b], 1);
        } else bk[r] = -1;
    }
    __syncthreads();
    for (int i = t; i < NB; i += 256) gbase[i] = atomicAdd(&gcnt[i], lcnt[i]);
    __syncthreads();
#pragma unroll
    for (int r = 0; r < PEPT; r++) {
        if (bk[r] >= 0) {
            int b = bk[r];
            int pos = gbase[b] + atomicAdd(&lcur[b], 1);
            bucketed[b * BCAP + pos] = pk[r];
        }
    }
}

__global__ __launch_bounds__(256) void k_bscan(const int* __restrict__ gcnt,
                                               int* __restrict__ base)
{
    __shared__ int s[256];
    int t = threadIdx.x;
    int v = (t < NB) ? gcnt[t] : 0;
    s[t] = v;
    __syncthreads();
#pragma unroll
    for (int off = 1; off < 256; off <<= 1) {
        int u = (t >= off) ? s[t - off] : 0;
        __syncthreads();
        s[t] += u;
        __syncthreads();
    }
    base[t] = s[t] - v;
}

// one block per bucket: local CSR in LDS, contiguous global writes
__global__ __launch_bounds__(512) void k_place(const int* __restrict__ bucketed,
                                               const int* __restrict__ gcnt,
                                               const int* __restrict__ base,
                                               int* __restrict__ csr,
                                               int* __restrict__ starts,
                                               int* __restrict__ cnt)
{
    __shared__ int scnt[512], sexc[512], scur[512];
    int b = blockIdx.x, t = threadIdx.x;
    int ecnt = gcnt[b];
    int ebase = base[b];
    const int* bp = bucketed + b * BCAP;

    scnt[t] = 0; scur[t] = 0;
    __syncthreads();
    for (int e = t; e < ecnt; e += 512) atomicAdd(&scnt[bp[e] >> 17], 1);
    __syncthreads();
    int v = scnt[t];
    sexc[t] = v;
    __syncthreads();
#pragma unroll
    for (int off = 1; off < 512; off <<= 1) {
        int u = (t >= off) ? sexc[t - off] : 0;
        __syncthreads();
        sexc[t] += u;
        __syncthreads();
    }
    int excl = sexc[t] - v;
    __syncthreads();
    sexc[t] = excl;
    __syncthreads();

    int node = b * 512 + t;
    if (node < N_NODES) { starts[node] = ebase + excl; cnt[node] = v; }

    for (int e = t; e < ecnt; e += 512) {
        int p = bp[e];
        int ld = p >> 17;
        int pos = ebase + sexc[ld] + atomicAdd(&scur[ld], 1);
        csr[pos] = p & 0x1FFFF;
    }
}

// ======================= Layer-1 src precompute: eq1 = exp(-(x*wq+bq)), v1 = x*wv+bv =======================
__global__ __launch_bounds__(256) void k_pre1(
    const float* __restrict__ x,
    const float* __restrict__ Wq, const float* __restrict__ bq,
    const float* __restrict__ Wv, const float* __restrict__ bv,
    u32* __restrict__ eqv1)
{
    int tid = blockIdx.x * 256 + threadIdx.x;
    if (tid >= N_NODES * 8) return;
    int i = tid >> 3, l = tid & 7;
    float xv = x[i];
    float4 wq = ((const float4*)Wq)[l], bq4 = ((const float4*)bq)[l];
    float4 wv = ((const float4*)Wv)[l], bv4 = ((const float4*)bv)[l];
    float e0 = __expf(-fmaf(xv, wq.x, bq4.x));
    float e1 = __expf(-fmaf(xv, wq.y, bq4.y));
    float e2 = __expf(-fmaf(xv, wq.z, bq4.z));
    float e3 = __expf(-fmaf(xv, wq.w, bq4.w));
    float v0 = fmaf(xv, wv.x, bv4.x);
    float v1 = fmaf(xv, wv.y, bv4.y);
    float v2 = fmaf(xv, wv.z, bv4.z);
    float v3 = fmaf(xv, wv.w, bv4.w);
    uint4 pk;
    pk.x = (u32)f2bf(e0) | ((u32)f2bf(e1) << 16);
    pk.y = (u32)f2bf(e2) | ((u32)f2bf(e3) << 16);
    pk.z = (u32)f2bf(v0) | ((u32)f2bf(v1) << 16);
    pk.w = (u32)f2bf(v2) | ((u32)f2bf(v3) << 16);
    ((uint4*)eqv1)[(size_t)i * 8 + l] = pk;
}

// 4 features of one gathered edge: acc += v * rcp(1 + ek*eq)
#define EDGE_ACC(P, ACC)                                                        \
    ACC.x += bf2f((u16)(P.z)) * rcpf(fmaf(ek.x, bf2f((u16)(P.x)), 1.0f));       \
    ACC.y += bf2f((u16)(P.z >> 16)) * rcpf(fmaf(ek.y, bf2f((u16)(P.x >> 16)), 1.0f)); \
    ACC.z += bf2f((u16)(P.w)) * rcpf(fmaf(ek.z, bf2f((u16)(P.y)), 1.0f));       \
    ACC.w += bf2f((u16)(P.w >> 16)) * rcpf(fmaf(ek.w, bf2f((u16)(P.y >> 16)), 1.0f));

// ======================= Layer 1: ResGated(1 -> 32) gather =======================
__global__ __launch_bounds__(256) void k_gath1(
    const float* __restrict__ x, const int* __restrict__ csr_src,
    const int* __restrict__ starts, const int* __restrict__ cnt,
    const u32* __restrict__ eqv1,
    const float* __restrict__ Wk, const float* __restrict__ bk,
    const float* __restrict__ Wskip, const float* __restrict__ b,
    float* __restrict__ h1)
{
    int tid = blockIdx.x * 256 + threadIdx.x;
    if (tid >= N_NODES * 8) return;
    int i = tid >> 3, l = tid & 7;

    float xd = x[i];
    float4 wk = ((const float4*)Wk)[l], bk4 = ((const float4*)bk)[l];
    float4 ek;
    ek.x = __expf(-fmaf(xd, wk.x, bk4.x));
    ek.y = __expf(-fmaf(xd, wk.y, bk4.y));
    ek.z = __expf(-fmaf(xd, wk.z, bk4.z));
    ek.w = __expf(-fmaf(xd, wk.w, bk4.w));

    int base = starts[i], deg = cnt[i];
    const uint4* qv = (const uint4*)eqv1;
    float4 a0 = make_float4(0.f, 0.f, 0.f, 0.f);
    float4 a1 = make_float4(0.f, 0.f, 0.f, 0.f);
    int e = 0;
    for (; e + 3 < deg; e += 4) {
        int s0 = csr_src[base + e];
        int s1 = csr_src[base + e + 1];
        int s2 = csr_src[base + e + 2];
        int s3 = csr_src[base + e + 3];
        uint4 p0 = qv[(size_t)s0 * 8 + l];
        uint4 p1 = qv[(size_t)s1 * 8 + l];
        uint4 p2 = qv[(size_t)s2 * 8 + l];
        uint4 p3 = qv[(size_t)s3 * 8 + l];
        EDGE_ACC(p0, a0) EDGE_ACC(p1, a1) EDGE_ACC(p2, a0) EDGE_ACC(p3, a1)
    }
    for (; e < deg; e++) {
        int s0 = csr_src[base + e];
        uint4 p0 = qv[(size_t)s0 * 8 + l];
        EDGE_ACC(p0, a0)
    }
    float4 ws4 = ((const float4*)Wskip)[l];
    float4 bb4 = ((const float4*)b)[l];
    float4 o = make_float4(a0.x + a1.x + fmaf(xd, ws4.x, bb4.x),
                           a0.y + a1.y + fmaf(xd, ws4.y, bb4.y),
                           a0.z + a1.z + fmaf(xd, ws4.z, bb4.z),
                           a0.w + a1.w + fmaf(xd, ws4.w, bb4.w));
    ((float4*)(h1 + (size_t)i * 32))[l] = o;
}

__device__ __forceinline__ float4 dot4(const float* __restrict__ h,
                                       const float* __restrict__ Wcol, int stride)
{
    float4 a = make_float4(0.f, 0.f, 0.f, 0.f);
#pragma unroll
    for (int k = 0; k < 32; k++) {
        float4 w = *(const float4*)(Wcol + k * stride);
        float hk = h[k];
        a.x = fmaf(hk, w.x, a.x);
        a.y = fmaf(hk, w.y, a.y);
        a.z = fmaf(hk, w.z, a.z);
        a.w = fmaf(hk, w.w, a.w);
    }
    return a;
}

// ======================= Layer 2: FiLM node-side =======================
__global__ __launch_bounds__(256) void k_node2(
    const float* __restrict__ h1,
    const float* __restrict__ Wlin, const float* __restrict__ Wfilm,
    const float* __restrict__ bfilm, const float* __restrict__ Wls,
    const float* __restrict__ Wfs,
    float* __restrict__ skip2, float* __restrict__ bg2, u16* __restrict__ xlb)
{
    __shared__ float sWlin[1024], sWfilm[2048], sWls[1024], sWfs[2048];
    int t = threadIdx.x;
    for (int idx = t; idx < 1024; idx += 256) sWlin[idx] = Wlin[idx];
    for (int idx = t; idx < 2048; idx += 256) sWfilm[idx] = Wfilm[idx];
    for (int idx = t; idx < 1024; idx += 256) sWls[idx] = Wls[idx];
    for (int idx = t; idx < 2048; idx += 256) sWfs[idx] = Wfs[idx];
    __syncthreads();

    int tid = blockIdx.x * 256 + t;
    if (tid >= N_NODES * 8) return;
    int i = tid >> 3, l = tid & 7;

    float h[32];
    const float4* hp = (const float4*)(h1 + (size_t)i * 32);
#pragma unroll
    for (int j = 0; j < 8; j++) {
        float4 v = hp[j];
        h[4 * j + 0] = fmaxf(v.x, 0.f);
        h[4 * j + 1] = fmaxf(v.y, 0.f);
        h[4 * j + 2] = fmaxf(v.z, 0.f);
        h[4 * j + 3] = fmaxf(v.w, 0.f);
    }

    float4 bs = dot4(h, sWfs + l * 4, 64);
    float4 gs = dot4(h, sWfs + 32 + l * 4, 64);
    float4 ls = dot4(h, sWls + l * 4, 32);
    float4 sk = make_float4(fmaxf(fmaf(gs.x, ls.x, bs.x), 0.f),
                            fmaxf(fmaf(gs.y, ls.y, bs.y), 0.f),
                            fmaxf(fmaf(gs.z, ls.z, bs.z), 0.f),
                            fmaxf(fmaf(gs.w, ls.w, bs.w), 0.f));
    ((float4*)(skip2 + (size_t)i * 32))[l] = sk;

    float4 bf0 = ((const float4*)bfilm)[l * 2];
    float4 bf1 = ((const float4*)bfilm)[l * 2 + 1];
    float4 f0 = dot4(h, sWfilm + l * 8, 64);
    float4 f1 = dot4(h, sWfilm + l * 8 + 4, 64);
    f0.x += bf0.x; f0.y += bf0.y; f0.z += bf0.z; f0.w += bf0.w;
    f1.x += bf1.x; f1.y += bf1.y; f1.z += bf1.z; f1.w += bf1.w;
    float4* bgp = (float4*)(bg2 + (size_t)i * 64);
    bgp[l * 2] = f0;
    bgp[l * 2 + 1] = f1;

    float4 xo = dot4(h, sWlin + l * 4, 32);
    ushort4 xp;
    xp.x = f2bf(xo.x); xp.y = f2bf(xo.y); xp.z = f2bf(xo.z); xp.w = f2bf(xo.w);
    ((ushort4*)xlb)[(size_t)i * 8 + l] = xp;
}

#define EDGE_ACC2(U, ACC)                                   \
    ACC.x += fmaxf(fmaf(ga.x, bf2f(U.x), be.x), 0.f);       \
    ACC.y += fmaxf(fmaf(ga.y, bf2f(U.y), be.y), 0.f);       \
    ACC.z += fmaxf(fmaf(ga.z, bf2f(U.z), be.z), 0.f);       \
    ACC.w += fmaxf(fmaf(ga.w, bf2f(U.w), be.w), 0.f);

// FiLM gather: h2 = relu(skip2 + mean relu(gamma_i*xl_s + beta_i))
__global__ __launch_bounds__(256) void k_gath2(
    const int* __restrict__ csr_src, const int* __restrict__ starts,
    const int* __restrict__ cnt,
    const float* __restrict__ bg2, const u16* __restrict__ xlb,
    const float* __restrict__ skip2, float* __restrict__ h2)
{
    int tid = blockIdx.x * 256 + threadIdx.x;
    if (tid >= N_NODES * 8) return;
    int i = tid >> 3, l = tid & 7;

    float4 be = ((const float4*)(bg2 + (size_t)i * 64))[l];
    float4 ga = ((const float4*)(bg2 + (size_t)i * 64 + 32))[l];

    int base = starts[i], deg = cnt[i];
    const ushort4* xp = (const ushort4*)xlb;
    float4 a0 = make_float4(0.f, 0.f, 0.f, 0.f);
    float4 a1 = make_float4(0.f, 0.f, 0.f, 0.f);
    int e = 0;
    for (; e + 3 < deg; e += 4) {
        int s0 = csr_src[base + e];
        int s1 = csr_src[base + e + 1];
        int s2 = csr_src[base + e + 2];
        int s3 = csr_src[base + e + 3];
        ushort4 u0 = xp[(size_t)s0 * 8 + l];
        ushort4 u1 = xp[(size_t)s1 * 8 + l];
        ushort4 u2 = xp[(size_t)s2 * 8 + l];
        ushort4 u3 = xp[(size_t)s3 * 8 + l];
        EDGE_ACC2(u0, a0) EDGE_ACC2(u1, a1) EDGE_ACC2(u2, a0) EDGE_ACC2(u3, a1)
    }
    for (; e < deg; e++) {
        int s0 = csr_src[base + e];
        ushort4 u0 = xp[(size_t)s0 * 8 + l];
        EDGE_ACC2(u0, a0)
    }
    float inv = rcpf(fmaxf((float)deg, 1.0f));
    float4 sk = ((const float4*)(skip2 + (size_t)i * 32))[l];
    float4 o = make_float4(fmaxf(fmaf(a0.x + a1.x, inv, sk.x), 0.f),
                           fmaxf(fmaf(a0.y + a1.y, inv, sk.y), 0.f),
                           fmaxf(fmaf(a0.z + a1.z, inv, sk.z), 0.f),
                           fmaxf(fmaf(a0.w + a1.w, inv, sk.w), 0.f));
    ((float4*)(h2 + (size_t)i * 32))[l] = o;
}

// ======================= Layer 3 node-side: ek3 = exp(-k), qvb = (exp(-q)|v) bf16 =======================
__global__ __launch_bounds__(256) void k_node3(
    const float* __restrict__ h2,
    const float* __restrict__ Wk, const float* __restrict__ bk,
    const float* __restrict__ Wq, const float* __restrict__ bq,
    const float* __restrict__ Wv, const float* __restrict__ bv,
    const float* __restrict__ Wskip, const float* __restrict__ b,
    float* __restrict__ ek3, u32* __restrict__ qvb, float* __restrict__ acc3)
{
    __shared__ float sWk[1024], sWq[1024], sWv[1024], sWs[1024];
    int t = threadIdx.x;
    for (int idx = t; idx < 1024; idx += 256) {
        sWk[idx] = Wk[idx];
        sWq[idx] = Wq[idx];
        sWv[idx] = Wv[idx];
        sWs[idx] = Wskip[idx];
    }
    __syncthreads();

    int tid = blockIdx.x * 256 + t;
    if (tid >= N_NODES * 8) return;
    int i = tid >> 3, l = tid & 7;

    float h[32];
    const float4* hp = (const float4*)(h2 + (size_t)i * 32);
#pragma unroll
    for (int j = 0; j < 8; j++) {
        float4 v = hp[j];
        h[4 * j + 0] = v.x; h[4 * j + 1] = v.y;
        h[4 * j + 2] = v.z; h[4 * j + 3] = v.w;
    }

    float4 bk4 = ((const float4*)bk)[l];
    float4 bq4 = ((const float4*)bq)[l];
    float4 bv4 = ((const float4*)bv)[l];
    float4 bb4 = ((const float4*)b)[l];

    float4 kk = dot4(h, sWk + l * 4, 32);
    float4 ekv;
    ekv.x = __expf(-(kk.x + bk4.x));
    ekv.y = __expf(-(kk.y + bk4.y));
    ekv.z = __expf(-(kk.z + bk4.z));
    ekv.w = __expf(-(kk.w + bk4.w));
    ((float4*)(ek3 + (size_t)i * 32))[l] = ekv;

    float4 qq = dot4(h, sWq + l * 4, 32);
    float4 vv = dot4(h, sWv + l * 4, 32);
    float eq0 = __expf(-(qq.x + bq4.x));
    float eq1 = __expf(-(qq.y + bq4.y));
    float eq2 = __expf(-(qq.z + bq4.z));
    float eq3 = __expf(-(qq.w + bq4.w));
    vv.x += bv4.x; vv.y += bv4.y; vv.z += bv4.z; vv.w += bv4.w;

    uint4 pk;
    pk.x = (u32)f2bf(eq0) | ((u32)f2bf(eq1) << 16);
    pk.y = (u32)f2bf(eq2) | ((u32)f2bf(eq3) << 16);
    pk.z = (u32)f2bf(vv.x) | ((u32)f2bf(vv.y) << 16);
    pk.w = (u32)f2bf(vv.z) | ((u32)f2bf(vv.w) << 16);
    ((uint4*)qvb)[(size_t)i * 8 + l] = pk;

    float4 ss = dot4(h, sWs + l * 4, 32);
    ss.x += bb4.x; ss.y += bb4.y; ss.z += bb4.z; ss.w += bb4.w;
    ((float4*)(acc3 + (size_t)i * 32))[l] = ss;
}

// ResGated gather: acc3 += sum v_s * rcp(1 + ek_i*eq_s)
__global__ __launch_bounds__(256) void k_gath3(
    const int* __restrict__ csr_src, const int* __restrict__ starts,
    const int* __restrict__ cnt,
    const float* __restrict__ ek3, const u32* __restrict__ qvb,
    float* __restrict__ acc3)
{
    int tid = blockIdx.x * 256 + threadIdx.x;
    if (tid >= N_NODES * 8) return;
    int i = tid >> 3, l = tid & 7;

    float4 ek = ((const float4*)(ek3 + (size_t)i * 32))[l];
    int base = starts[i], deg = cnt[i];
    const uint4* qv = (const uint4*)qvb;
    float4 a0 = make_float4(0.f, 0.f, 0.f, 0.f);
    float4 a1 = make_float4(0.f, 0.f, 0.f, 0.f);
    int e = 0;
    for (; e + 3 < deg; e += 4) {
        int s0 = csr_src[base + e];
        int s1 = csr_src[base + e + 1];
        int s2 = csr_src[base + e + 2];
        int s3 = csr_src[base + e + 3];
        uint4 p0 = qv[(size_t)s0 * 8 + l];
        uint4 p1 = qv[(size_t)s1 * 8 + l];
        uint4 p2 = qv[(size_t)s2 * 8 + l];
        uint4 p3 = qv[(size_t)s3 * 8 + l];
        EDGE_ACC(p0, a0) EDGE_ACC(p1, a1) EDGE_ACC(p2, a0) EDGE_ACC(p3, a1)
    }
    for (; e < deg; e++) {
        int s0 = csr_src[base + e];
        uint4 p0 = qv[(size_t)s0 * 8 + l];
        EDGE_ACC(p0, a0)
    }
    float4* op = (float4*)(acc3 + (size_t)i * 32) + l;
    float4 cur = *op;
    cur.x += a0.x + a1.x;
    cur.y += a0.y + a1.y;
    cur.z += a0.z + a1.z;
    cur.w += a0.w + a1.w;
    *op = cur;
}

// ======================= pool =======================
__global__ __launch_bounds__(256) void k_gstart(const int* __restrict__ batch,
                                                int* __restrict__ gstart)
{
    int g = blockIdx.x * 256 + threadIdx.x;
    if (g > N_GRAPH) return;
    int lo = 0, hi = N_NODES;
    while (lo < hi) {
        int mid = (lo + hi) >> 1;
        if (batch[mid] < g) lo = mid + 1; else hi = mid;
    }
    gstart[g] = lo;
}

__global__ __launch_bounds__(256) void k_pool(
    const float* __restrict__ h3, const int* __restrict__ gstart,
    float* __restrict__ gmean)
{
    int tid = blockIdx.x * 256 + threadIdx.x;
    int g = tid >> 6;
    if (g >= N_GRAPH) return;
    int lane = tid & 63;
    int sub = lane >> 3, fg = lane & 7;
    int gs = gstart[g], ge = gstart[g + 1];

    float4 a = make_float4(0.f, 0.f, 0.f, 0.f);
    for (int j = gs + sub; j < ge; j += 8) {
        float4 v = ((const float4*)(h3 + (size_t)j * 32))[fg];
        a.x += v.x; a.y += v.y; a.z += v.z; a.w += v.w;
    }
#pragma unroll
    for (int off = 8; off < 64; off <<= 1) {
        a.x += __shfl_xor(a.x, off);
        a.y += __shfl_xor(a.y, off);
        a.z += __shfl_xor(a.z, off);
        a.w += __shfl_xor(a.w, off);
    }
    if (sub == 0) {
        float inv = 1.0f / fmaxf((float)(ge - gs), 1.0f);
        a.x *= inv; a.y *= inv; a.z *= inv; a.w *= inv;
        ((float4*)(gmean + (size_t)g * 32))[fg] = a;
    }
}

__global__ __launch_bounds__(256) void k_final(
    const float* __restrict__ gmean,
    const float* __restrict__ linW, const float* __restrict__ linb,
    float* __restrict__ out)
{
    int tid = blockIdx.x * 256 + threadIdx.x;
    if (tid >= N_GRAPH * 10) return;
    int g = tid / 10, c = tid % 10;
    const float* gr = gmean + (size_t)g * 32;
    float a = 0.f;
#pragma unroll
    for (int k = 0; k < 32; k++) a = fmaf(gr[k], linW[k * 10 + c], a);
    out[tid] = a + linb[c];
}

extern "C" void kernel_launch(void* const* d_in, const int* in_sizes, int n_in,
                              void* d_out, int out_size, void* d_ws, size_t ws_size,
                              hipStream_t stream)
{
    const float* x      = (const float*)d_in[0];
    const int*   ei     = (const int*)d_in[1];
    const int*   batch  = (const int*)d_in[2];
    const float* c1_Wk   = (const float*)d_in[4];
    const float* c1_bk   = (const float*)d_in[5];
    const float* c1_Wq   = (const float*)d_in[6];
    const float* c1_bq   = (const float*)d_in[7];
    const float* c1_Wv   = (const float*)d_in[8];
    const float* c1_bv   = (const float*)d_in[9];
    const float* c1_Wsk  = (const float*)d_in[10];
    const float* c1_b    = (const float*)d_in[11];
    const float* c2_Wlin = (const float*)d_in[12];
    const float* c2_Wfilm= (const float*)d_in[13];
    const float* c2_bfilm= (const float*)d_in[14];
    const float* c2_Wls  = (const float*)d_in[15];
    const float* c2_Wfs  = (const float*)d_in[16];
    const float* c3_Wk   = (const float*)d_in[17];
    const float* c3_bk   = (const float*)d_in[18];
    const float* c3_Wq   = (const float*)d_in[19];
    const float* c3_bq   = (const float*)d_in[20];
    const float* c3_Wv   = (const float*)d_in[21];
    const float* c3_bv   = (const float*)d_in[22];
    const float* c3_Wsk  = (const float*)d_in[23];
    const float* c3_b    = (const float*)d_in[24];
    const float* lin_W   = (const float*)d_in[25];
    const float* lin_b   = (const float*)d_in[26];
    float* out = (float*)d_out;

    const size_t N = N_NODES;

    // ---- workspace layout ----
    int* gcnt    = (int*)d_ws;              // 256 (zeroed)
    int* bbase   = gcnt + 256;              // 256
    int* igstart = bbase + 256;             // 1056
    int* bucketed= igstart + 1056;          // NB*BCAP
    int* icsr    = bucketed + NB * BCAP;    // E
    int* istarts = icsr + N_EDGES;          // N
    int* icnt    = istarts + N;             // N
    float* h1    = (float*)(icnt + N);      // N*32 (reused as h2)
    float* skip2 = h1 + N * 32;             // N*32 (reused as ek3)
    float* bg2   = skip2 + N * 32;          // N*64 (lower reused as qvb u32, upper as acc3/h3)
    u16*   xlb   = (u16*)(bg2 + N * 64);    // N*32 bf16
    u32*   eqv1  = (u32*)(xlb + N * 32);    // N*32 u32 (layer-1 eq|v bf16 rows)
    float* gmean = (float*)(eqv1 + N * 32); // G*32

    hipMemsetAsync(gcnt, 0, 256 * sizeof(int), stream);

    const int TB = 256;
    int gPart  = (N_EDGES + 256 * PEPT - 1) / (256 * PEPT);  // 391
    int gNode8 = (N_NODES * 8 + TB - 1) / TB;                // 3125
    int gFin   = (N_GRAPH * 10 + TB - 1) / TB;               // 40

    // CSR build
    k_partition<<<gPart, TB, 0, stream>>>(ei, gcnt, bucketed);
    k_bscan<<<1, 256, 0, stream>>>(gcnt, bbase);
    k_place<<<NB, 512, 0, stream>>>(bucketed, gcnt, bbase, icsr, istarts, icnt);
    k_gstart<<<5, TB, 0, stream>>>(batch, igstart);

    // Layer 1: src precompute + gather (exp-hoisted)
    k_pre1<<<gNode8, TB, 0, stream>>>(x, c1_Wq, c1_bq, c1_Wv, c1_bv, eqv1);
    k_gath1<<<gNode8, TB, 0, stream>>>(x, icsr, istarts, icnt, eqv1,
                                       c1_Wk, c1_bk, c1_Wsk, c1_b, h1);
    // Layer 2 (FiLM)
    k_node2<<<gNode8, TB, 0, stream>>>(h1, c2_Wlin, c2_Wfilm, c2_bfilm,
                                       c2_Wls, c2_Wfs, skip2, bg2, xlb);
    float* h2 = h1;
    k_gath2<<<gNode8, TB, 0, stream>>>(icsr, istarts, icnt, bg2, xlb, skip2, h2);
    // Layer 3 (ResGated, exp-hoisted)
    float* ek3  = skip2;
    u32*   qvb  = (u32*)bg2;
    float* acc3 = bg2 + N * 32;
    k_node3<<<gNode8, TB, 0, stream>>>(h2, c3_Wk, c3_bk, c3_Wq, c3_bq,
                                       c3_Wv, c3_bv, c3_Wsk, c3_b,
                                       ek3, qvb, acc3);
    k_gath3<<<gNode8, TB, 0, stream>>>(icsr, istarts, icnt, ek3, qvb, acc3);
    // Pool + classifier
    k_pool<<<256, TB, 0, stream>>>(acc3, igstart, gmean);
    k_final<<<gFin, TB, 0, stream>>>(gmean, lin_W, lin_b, out);
}

// Round 8
// 304.461 us; speedup vs baseline: 1.6764x; 1.0292x over previous
//
#include <hip/hip_runtime.h>

#define N_NODES 100000
#define N_EDGES 1600000
#define N_GRAPH 1024
#define NB      196      // buckets of 512 nodes
#define BCAP    10240    // bucket capacity (mean 8192, ~22 sigma slack)
#define PEPT    16       // edges per thread in partition

typedef unsigned short u16;
typedef unsigned int   u32;

__device__ __forceinline__ u16 f2bf(float f) {
    u32 u = __float_as_uint(f);
    u += 0x7FFFu + ((u >> 16) & 1u);
    return (u16)(u >> 16);
}
__device__ __forceinline__ float bf2f(u16 h) { return __uint_as_float(((u32)h) << 16); }
__device__ __forceinline__ float rcpf(float x) { return __builtin_amdgcn_rcpf(x); }

// ======================= CSR build: bucket partition =======================
__global__ __launch_bounds__(256) void k_partition(const int* __restrict__ ei,
                                                   int* __restrict__ gcnt,
                                                   int* __restrict__ bucketed)
{
    __shared__ int lcnt[NB], gbase[NB], lcur[NB];
    int t = threadIdx.x;
    for (int i = t; i < NB; i += 256) { lcnt[i] = 0; lcur[i] = 0; }
    __syncthreads();

    int ebase = blockIdx.x * (256 * PEPT);
    int pk[PEPT], bk[PEPT];
#pragma unroll
    for (int r = 0; r < PEPT; r++) {
        int e = ebase + r * 256 + t;
        if (e < N_EDGES) {
            int d = ei[N_EDGES + e];
            int s = ei[e];
            int b = d >> 9;
            bk[r] = b;
            pk[r] = ((d & 511) << 17) | s;
            atomicAdd(&lcnt[b], 1);
        } else bk[r] = -1;
    }
    __syncthreads();
    for (int i = t; i < NB; i += 256) gbase[i] = atomicAdd(&gcnt[i], lcnt[i]);
    __syncthreads();
#pragma unroll
    for (int r = 0; r < PEPT; r++) {
        if (bk[r] >= 0) {
            int b = bk[r];
            int pos = gbase[b] + atomicAdd(&lcur[b], 1);
            bucketed[b * BCAP + pos] = pk[r];
        }
    }
}

__global__ __launch_bounds__(256) void k_bscan(const int* __restrict__ gcnt,
                                               int* __restrict__ base)
{
    __shared__ int s[256];
    int t = threadIdx.x;
    int v = (t < NB) ? gcnt[t] : 0;
    s[t] = v;
    __syncthreads();
#pragma unroll
    for (int off = 1; off < 256; off <<= 1) {
        int u = (t >= off) ? s[t - off] : 0;
        __syncthreads();
        s[t] += u;
        __syncthreads();
    }
    base[t] = s[t] - v;
}

// one block per bucket: local CSR in LDS, contiguous global writes
__global__ __launch_bounds__(512) void k_place(const int* __restrict__ bucketed,
                                               const int* __restrict__ gcnt,
                                               const int* __restrict__ base,
                                               int* __restrict__ csr,
                                               int* __restrict__ starts,
                                               int* __restrict__ cnt)
{
    __shared__ int scnt[512], sexc[512], scur[512];
    int b = blockIdx.x, t = threadIdx.x;
    int ecnt = gcnt[b];
    int ebase = base[b];
    const int* bp = bucketed + b * BCAP;

    scnt[t] = 0; scur[t] = 0;
    __syncthreads();
    for (int e = t; e < ecnt; e += 512) atomicAdd(&scnt[bp[e] >> 17], 1);
    __syncthreads();
    int v = scnt[t];
    sexc[t] = v;
    __syncthreads();
#pragma unroll
    for (int off = 1; off < 512; off <<= 1) {
        int u = (t >= off) ? sexc[t - off] : 0;
        __syncthreads();
        sexc[t] += u;
        __syncthreads();
    }
    int excl = sexc[t] - v;
    __syncthreads();
    sexc[t] = excl;
    __syncthreads();

    int node = b * 512 + t;
    if (node < N_NODES) { starts[node] = ebase + excl; cnt[node] = v; }

    for (int e = t; e < ecnt; e += 512) {
        int p = bp[e];
        int ld = p >> 17;
        int pos = ebase + sexc[ld] + atomicAdd(&scur[ld], 1);
        csr[pos] = p & 0x1FFFF;
    }
}

__global__ __launch_bounds__(256) void k_gstart(const int* __restrict__ batch,
                                                int* __restrict__ gstart)
{
    int g = blockIdx.x * 256 + threadIdx.x;
    if (g > N_GRAPH) return;
    int lo = 0, hi = N_NODES;
    while (lo < hi) {
        int mid = (lo + hi) >> 1;
        if (batch[mid] < g) lo = mid + 1; else hi = mid;
    }
    gstart[g] = lo;
}

// ======================= Layer 1: ResGated(1 -> 32), x-direct gather =======================
// x is 400 KB -> L2-resident per XCD; compute eq = exp(-q_s) inline, sigma via rcp.
#define EDGE1(XS, ACC) {                                                     \
    ACC.x += fmaf(XS, wv.x, bv4.x) *                                         \
             rcpf(fmaf(ek.x, __expf(-fmaf(XS, wq.x, bq4.x)), 1.0f));         \
    ACC.y += fmaf(XS, wv.y, bv4.y) *                                         \
             rcpf(fmaf(ek.y, __expf(-fmaf(XS, wq.y, bq4.y)), 1.0f));         \
    ACC.z += fmaf(XS, wv.z, bv4.z) *                                         \
             rcpf(fmaf(ek.z, __expf(-fmaf(XS, wq.z, bq4.z)), 1.0f));         \
    ACC.w += fmaf(XS, wv.w, bv4.w) *                                         \
             rcpf(fmaf(ek.w, __expf(-fmaf(XS, wq.w, bq4.w)), 1.0f)); }

__global__ __launch_bounds__(256) void k_gath1(
    const float* __restrict__ x, const int* __restrict__ csr_src,
    const int* __restrict__ starts, const int* __restrict__ cnt,
    const float* __restrict__ Wk, const float* __restrict__ bk,
    const float* __restrict__ Wq, const float* __restrict__ bq,
    const float* __restrict__ Wv, const float* __restrict__ bv,
    const float* __restrict__ Wskip, const float* __restrict__ b,
    float* __restrict__ h1)
{
    int tid = blockIdx.x * 256 + threadIdx.x;
    int i = tid >> 3, l = tid & 7;

    float xd = x[i];
    float4 wk = ((const float4*)Wk)[l], bk4 = ((const float4*)bk)[l];
    float4 wq = ((const float4*)Wq)[l], bq4 = ((const float4*)bq)[l];
    float4 wv = ((const float4*)Wv)[l], bv4 = ((const float4*)bv)[l];
    float4 ek;
    ek.x = __expf(-fmaf(xd, wk.x, bk4.x));
    ek.y = __expf(-fmaf(xd, wk.y, bk4.y));
    ek.z = __expf(-fmaf(xd, wk.z, bk4.z));
    ek.w = __expf(-fmaf(xd, wk.w, bk4.w));

    int base = starts[i], deg = cnt[i];
    float4 a0 = make_float4(0.f, 0.f, 0.f, 0.f);
    float4 a1 = make_float4(0.f, 0.f, 0.f, 0.f);
    int e = 0;
    for (; e + 1 < deg; e += 2) {
        int s0 = csr_src[base + e];
        int s1 = csr_src[base + e + 1];
        float x0 = x[s0], x1 = x[s1];
        EDGE1(x0, a0) EDGE1(x1, a1)
    }
    if (e < deg) {
        float x0 = x[csr_src[base + e]];
        EDGE1(x0, a0)
    }
    float4 ws4 = ((const float4*)Wskip)[l];
    float4 bb4 = ((const float4*)b)[l];
    float4 o = make_float4(a0.x + a1.x + fmaf(xd, ws4.x, bb4.x),
                           a0.y + a1.y + fmaf(xd, ws4.y, bb4.y),
                           a0.z + a1.z + fmaf(xd, ws4.z, bb4.z),
                           a0.w + a1.w + fmaf(xd, ws4.w, bb4.w));
    ((float4*)(h1 + (size_t)i * 32))[l] = o;
}

__device__ __forceinline__ float4 dot4(const float* __restrict__ h,
                                       const float* __restrict__ Wcol, int stride)
{
    float4 a = make_float4(0.f, 0.f, 0.f, 0.f);
#pragma unroll
    for (int k = 0; k < 32; k++) {
        float4 w = *(const float4*)(Wcol + k * stride);
        float hk = h[k];
        a.x = fmaf(hk, w.x, a.x);
        a.y = fmaf(hk, w.y, a.y);
        a.z = fmaf(hk, w.z, a.z);
        a.w = fmaf(hk, w.w, a.w);
    }
    return a;
}

// ======================= Layer 2: FiLM node-side (bf16 outputs) =======================
__global__ __launch_bounds__(256) void k_node2(
    const float* __restrict__ h1,
    const float* __restrict__ Wlin, const float* __restrict__ Wfilm,
    const float* __restrict__ bfilm, const float* __restrict__ Wls,
    const float* __restrict__ Wfs,
    u16* __restrict__ skip2b, u16* __restrict__ bg2b, u16* __restrict__ xlb)
{
    __shared__ float sWlin[1024], sWfilm[2048], sWls[1024], sWfs[2048];
    int t = threadIdx.x;
    for (int idx = t; idx < 1024; idx += 256) sWlin[idx] = Wlin[idx];
    for (int idx = t; idx < 2048; idx += 256) sWfilm[idx] = Wfilm[idx];
    for (int idx = t; idx < 1024; idx += 256) sWls[idx] = Wls[idx];
    for (int idx = t; idx < 2048; idx += 256) sWfs[idx] = Wfs[idx];
    __syncthreads();

    int tid = blockIdx.x * 256 + t;
    int i = tid >> 3, l = tid & 7;

    float h[32];
    const float4* hp = (const float4*)(h1 + (size_t)i * 32);
#pragma unroll
    for (int j = 0; j < 8; j++) {
        float4 v = hp[j];
        h[4 * j + 0] = fmaxf(v.x, 0.f);
        h[4 * j + 1] = fmaxf(v.y, 0.f);
        h[4 * j + 2] = fmaxf(v.z, 0.f);
        h[4 * j + 3] = fmaxf(v.w, 0.f);
    }

    float4 bs = dot4(h, sWfs + l * 4, 64);
    float4 gs = dot4(h, sWfs + 32 + l * 4, 64);
    float4 ls = dot4(h, sWls + l * 4, 32);
    ushort4 sku;
    sku.x = f2bf(fmaxf(fmaf(gs.x, ls.x, bs.x), 0.f));
    sku.y = f2bf(fmaxf(fmaf(gs.y, ls.y, bs.y), 0.f));
    sku.z = f2bf(fmaxf(fmaf(gs.z, ls.z, bs.z), 0.f));
    sku.w = f2bf(fmaxf(fmaf(gs.w, ls.w, bs.w), 0.f));
    ((ushort4*)skip2b)[(size_t)i * 8 + l] = sku;

    float4 bf0 = ((const float4*)bfilm)[l * 2];
    float4 bf1 = ((const float4*)bfilm)[l * 2 + 1];
    float4 f0 = dot4(h, sWfilm + l * 8, 64);
    float4 f1 = dot4(h, sWfilm + l * 8 + 4, 64);
    f0.x += bf0.x; f0.y += bf0.y; f0.z += bf0.z; f0.w += bf0.w;
    f1.x += bf1.x; f1.y += bf1.y; f1.z += bf1.z; f1.w += bf1.w;
    uint4 pk;
    pk.x = (u32)f2bf(f0.x) | ((u32)f2bf(f0.y) << 16);
    pk.y = (u32)f2bf(f0.z) | ((u32)f2bf(f0.w) << 16);
    pk.z = (u32)f2bf(f1.x) | ((u32)f2bf(f1.y) << 16);
    pk.w = (u32)f2bf(f1.z) | ((u32)f2bf(f1.w) << 16);
    ((uint4*)bg2b)[(size_t)i * 8 + l] = pk;   // row = 64 bf16: [beta(32) | gamma(32)]

    float4 xo = dot4(h, sWlin + l * 4, 32);
    ushort4 xp;
    xp.x = f2bf(xo.x); xp.y = f2bf(xo.y); xp.z = f2bf(xo.z); xp.w = f2bf(xo.w);
    ((ushort4*)xlb)[(size_t)i * 8 + l] = xp;
}

#define EDGE_ACC2(U, ACC)                                   \
    ACC.x += fmaxf(fmaf(ga.x, bf2f(U.x), be.x), 0.f);       \
    ACC.y += fmaxf(fmaf(ga.y, bf2f(U.y), be.y), 0.f);       \
    ACC.z += fmaxf(fmaf(ga.z, bf2f(U.z), be.z), 0.f);       \
    ACC.w += fmaxf(fmaf(ga.w, bf2f(U.w), be.w), 0.f);

// FiLM gather: h2 = relu(skip2 + mean relu(gamma_i*xl_s + beta_i))
__global__ __launch_bounds__(256) void k_gath2(
    const int* __restrict__ csr_src, const int* __restrict__ starts,
    const int* __restrict__ cnt,
    const u16* __restrict__ bg2b, const u16* __restrict__ xlb,
    const u16* __restrict__ skip2b, float* __restrict__ h2)
{
    int tid = blockIdx.x * 256 + threadIdx.x;
    int i = tid >> 3, l = tid & 7;

    const u16* row = bg2b + (size_t)i * 64;
    ushort4 beu = *(const ushort4*)(row + l * 4);
    ushort4 gau = *(const ushort4*)(row + 32 + l * 4);
    float4 be = make_float4(bf2f(beu.x), bf2f(beu.y), bf2f(beu.z), bf2f(beu.w));
    float4 ga = make_float4(bf2f(gau.x), bf2f(gau.y), bf2f(gau.z), bf2f(gau.w));

    int base = starts[i], deg = cnt[i];
    const ushort4* xp = (const ushort4*)xlb;
    float4 a0 = make_float4(0.f, 0.f, 0.f, 0.f);
    float4 a1 = make_float4(0.f, 0.f, 0.f, 0.f);
    int e = 0;
    for (; e + 3 < deg; e += 4) {
        int s0 = csr_src[base + e];
        int s1 = csr_src[base + e + 1];
        int s2 = csr_src[base + e + 2];
        int s3 = csr_src[base + e + 3];
        ushort4 u0 = xp[(size_t)s0 * 8 + l];
        ushort4 u1 = xp[(size_t)s1 * 8 + l];
        ushort4 u2 = xp[(size_t)s2 * 8 + l];
        ushort4 u3 = xp[(size_t)s3 * 8 + l];
        EDGE_ACC2(u0, a0) EDGE_ACC2(u1, a1) EDGE_ACC2(u2, a0) EDGE_ACC2(u3, a1)
    }
    for (; e < deg; e++) {
        ushort4 u0 = xp[(size_t)csr_src[base + e] * 8 + l];
        EDGE_ACC2(u0, a0)
    }
    float inv = rcpf(fmaxf((float)deg, 1.0f));
    ushort4 sku = ((const ushort4*)skip2b)[(size_t)i * 8 + l];
    float4 o = make_float4(
        fmaxf(fmaf(a0.x + a1.x, inv, bf2f(sku.x)), 0.f),
        fmaxf(fmaf(a0.y + a1.y, inv, bf2f(sku.y)), 0.f),
        fmaxf(fmaf(a0.z + a1.z, inv, bf2f(sku.z)), 0.f),
        fmaxf(fmaf(a0.w + a1.w, inv, bf2f(sku.w)), 0.f));
    ((float4*)(h2 + (size_t)i * 32))[l] = o;
}

// ======================= Layer 3 node-side: ek3 bf16, qvb = (exp(-q)|v) bf16, acc3 = skip =======================
__global__ __launch_bounds__(256) void k_node3(
    const float* __restrict__ h2,
    const float* __restrict__ Wk, const float* __restrict__ bk,
    const float* __restrict__ Wq, const float* __restrict__ bq,
    const float* __restrict__ Wv, const float* __restrict__ bv,
    const float* __restrict__ Wskip, const float* __restrict__ b,
    u16* __restrict__ ek3b, u32* __restrict__ qvb, float* __restrict__ acc3)
{
    __shared__ float sWk[1024], sWq[1024], sWv[1024], sWs[1024];
    int t = threadIdx.x;
    for (int idx = t; idx < 1024; idx += 256) {
        sWk[idx] = Wk[idx];
        sWq[idx] = Wq[idx];
        sWv[idx] = Wv[idx];
        sWs[idx] = Wskip[idx];
    }
    __syncthreads();

    int tid = blockIdx.x * 256 + t;
    int i = tid >> 3, l = tid & 7;

    float h[32];
    const float4* hp = (const float4*)(h2 + (size_t)i * 32);
#pragma unroll
    for (int j = 0; j < 8; j++) {
        float4 v = hp[j];
        h[4 * j + 0] = v.x; h[4 * j + 1] = v.y;
        h[4 * j + 2] = v.z; h[4 * j + 3] = v.w;
    }

    float4 bk4 = ((const float4*)bk)[l];
    float4 bq4 = ((const float4*)bq)[l];
    float4 bv4 = ((const float4*)bv)[l];
    float4 bb4 = ((const float4*)b)[l];

    float4 kk = dot4(h, sWk + l * 4, 32);
    ushort4 eku;
    eku.x = f2bf(__expf(-(kk.x + bk4.x)));
    eku.y = f2bf(__expf(-(kk.y + bk4.y)));
    eku.z = f2bf(__expf(-(kk.z + bk4.z)));
    eku.w = f2bf(__expf(-(kk.w + bk4.w)));
    ((ushort4*)ek3b)[(size_t)i * 8 + l] = eku;

    float4 qq = dot4(h, sWq + l * 4, 32);
    float4 vv = dot4(h, sWv + l * 4, 32);
    float eq0 = __expf(-(qq.x + bq4.x));
    float eq1 = __expf(-(qq.y + bq4.y));
    float eq2 = __expf(-(qq.z + bq4.z));
    float eq3 = __expf(-(qq.w + bq4.w));
    vv.x += bv4.x; vv.y += bv4.y; vv.z += bv4.z; vv.w += bv4.w;

    uint4 pk;
    pk.x = (u32)f2bf(eq0) | ((u32)f2bf(eq1) << 16);
    pk.y = (u32)f2bf(eq2) | ((u32)f2bf(eq3) << 16);
    pk.z = (u32)f2bf(vv.x) | ((u32)f2bf(vv.y) << 16);
    pk.w = (u32)f2bf(vv.z) | ((u32)f2bf(vv.w) << 16);
    ((uint4*)qvb)[(size_t)i * 8 + l] = pk;

    float4 ss = dot4(h, sWs + l * 4, 32);
    ss.x += bb4.x; ss.y += bb4.y; ss.z += bb4.z; ss.w += bb4.w;
    ((float4*)(acc3 + (size_t)i * 32))[l] = ss;
}

// 4 features of one gathered edge: acc += v * rcp(1 + ek*eq)
#define EDGE_ACC(P, ACC)                                                        \
    ACC.x += bf2f((u16)(P.z)) * rcpf(fmaf(ek.x, bf2f((u16)(P.x)), 1.0f));       \
    ACC.y += bf2f((u16)(P.z >> 16)) * rcpf(fmaf(ek.y, bf2f((u16)(P.x >> 16)), 1.0f)); \
    ACC.z += bf2f((u16)(P.w)) * rcpf(fmaf(ek.z, bf2f((u16)(P.y)), 1.0f));       \
    ACC.w += bf2f((u16)(P.w >> 16)) * rcpf(fmaf(ek.w, bf2f((u16)(P.y >> 16)), 1.0f));

// ResGated gather + fused mean-pool: h3 accumulated straight into gsum[batch[i]]
__global__ __launch_bounds__(256) void k_gath3p(
    const int* __restrict__ csr_src, const int* __restrict__ starts,
    const int* __restrict__ cnt,
    const u16* __restrict__ ek3b, const u32* __restrict__ qvb,
    const float* __restrict__ acc3, const int* __restrict__ batch,
    float* __restrict__ gsum)
{
    __shared__ float sg[8][32];
    int t = threadIdx.x;
    int tid = blockIdx.x * 256 + t;
    int i = tid >> 3, l = tid & 7;     // grid exact: N*8 == 3125*256

    sg[t >> 5][t & 31] = 0.f;
    int gmin = batch[blockIdx.x * 32];
    __syncthreads();

    ushort4 eku = ((const ushort4*)ek3b)[(size_t)i * 8 + l];
    float4 ek = make_float4(bf2f(eku.x), bf2f(eku.y), bf2f(eku.z), bf2f(eku.w));
    int base = starts[i], deg = cnt[i];
    const uint4* qv = (const uint4*)qvb;
    float4 a0 = make_float4(0.f, 0.f, 0.f, 0.f);
    float4 a1 = make_float4(0.f, 0.f, 0.f, 0.f);
    int e = 0;
    for (; e + 3 < deg; e += 4) {
        int s0 = csr_src[base + e];
        int s1 = csr_src[base + e + 1];
        int s2 = csr_src[base + e + 2];
        int s3 = csr_src[base + e + 3];
        uint4 p0 = qv[(size_t)s0 * 8 + l];
        uint4 p1 = qv[(size_t)s1 * 8 + l];
        uint4 p2 = qv[(size_t)s2 * 8 + l];
        uint4 p3 = qv[(size_t)s3 * 8 + l];
        EDGE_ACC(p0, a0) EDGE_ACC(p1, a1) EDGE_ACC(p2, a0) EDGE_ACC(p3, a1)
    }
    for (; e < deg; e++) {
        uint4 p0 = qv[(size_t)csr_src[base + e] * 8 + l];
        EDGE_ACC(p0, a0)
    }
    float4 ss = ((const float4*)(acc3 + (size_t)i * 32))[l];
    float4 o = make_float4(ss.x + a0.x + a1.x, ss.y + a0.y + a1.y,
                           ss.z + a0.z + a1.z, ss.w + a0.w + a1.w);

    int g = batch[i];
    int slot = g - gmin;
    if (slot < 8) {
        atomicAdd(&sg[slot][l * 4 + 0], o.x);
        atomicAdd(&sg[slot][l * 4 + 1], o.y);
        atomicAdd(&sg[slot][l * 4 + 2], o.z);
        atomicAdd(&sg[slot][l * 4 + 3], o.w);
    } else {  // defensive fallback (not expected with sorted batch)
        atomicAdd(&gsum[(size_t)g * 32 + l * 4 + 0], o.x);
        atomicAdd(&gsum[(size_t)g * 32 + l * 4 + 1], o.y);
        atomicAdd(&gsum[(size_t)g * 32 + l * 4 + 2], o.z);
        atomicAdd(&gsum[(size_t)g * 32 + l * 4 + 3], o.w);
    }
    __syncthreads();
    int slot2 = t >> 5, feat = t & 31;
    float v = sg[slot2][feat];
    int gout = gmin + slot2;
    if (v != 0.f && gout < N_GRAPH)
        atomicAdd(&gsum[(size_t)gout * 32 + feat], v);
}

// out[g,c] = dot(gsum[g]/cnt_g, linW[:,c]) + linb[c]
__global__ __launch_bounds__(256) void k_final(
    const float* __restrict__ gsum, const int* __restrict__ gstart,
    const float* __restrict__ linW, const float* __restrict__ linb,
    float* __restrict__ out)
{
    int tid = blockIdx.x * 256 + threadIdx.x;
    if (tid >= N_GRAPH * 10) return;
    int g = tid / 10, c = tid % 10;
    float inv = rcpf(fmaxf((float)(gstart[g + 1] - gstart[g]), 1.0f));
    const float* gr = gsum + (size_t)g * 32;
    float a = 0.f;
#pragma unroll
    for (int k = 0; k < 32; k++) a = fmaf(gr[k], linW[k * 10 + c], a);
    out[tid] = fmaf(a, inv, linb[c]);
}

extern "C" void kernel_launch(void* const* d_in, const int* in_sizes, int n_in,
                              void* d_out, int out_size, void* d_ws, size_t ws_size,
                              hipStream_t stream)
{
    const float* x      = (const float*)d_in[0];
    const int*   ei     = (const int*)d_in[1];
    const int*   batch  = (const int*)d_in[2];
    const float* c1_Wk   = (const float*)d_in[4];
    const float* c1_bk   = (const float*)d_in[5];
    const float* c1_Wq   = (const float*)d_in[6];
    const float* c1_bq   = (const float*)d_in[7];
    const float* c1_Wv   = (const float*)d_in[8];
    const float* c1_bv   = (const float*)d_in[9];
    const float* c1_Wsk  = (const float*)d_in[10];
    const float* c1_b    = (const float*)d_in[11];
    const float* c2_Wlin = (const float*)d_in[12];
    const float* c2_Wfilm= (const float*)d_in[13];
    const float* c2_bfilm= (const float*)d_in[14];
    const float* c2_Wls  = (const float*)d_in[15];
    const float* c2_Wfs  = (const float*)d_in[16];
    const float* c3_Wk   = (const float*)d_in[17];
    const float* c3_bk   = (const float*)d_in[18];
    const float* c3_Wq   = (const float*)d_in[19];
    const float* c3_bq   = (const float*)d_in[20];
    const float* c3_Wv   = (const float*)d_in[21];
    const float* c3_bv   = (const float*)d_in[22];
    const float* c3_Wsk  = (const float*)d_in[23];
    const float* c3_b    = (const float*)d_in[24];
    const float* lin_W   = (const float*)d_in[25];
    const float* lin_b   = (const float*)d_in[26];
    float* out = (float*)d_out;

    const size_t N = N_NODES;

    // ---- workspace layout ----
    int*   gcnt    = (int*)d_ws;                    // 256 (zeroed)
    float* gsum    = (float*)(gcnt + 256);          // G*32 (zeroed, same memset)
    int*   bbase   = (int*)(gsum + N_GRAPH * 32);   // 256
    int*   igstart = bbase + 256;                   // 1056
    int*   bucketed= igstart + 1056;                // NB*BCAP
    int*   icsr    = bucketed + NB * BCAP;          // E
    int*   istarts = icsr + N_EDGES;                // N
    int*   icnt    = istarts + N;                   // N
    float* h1      = (float*)(icnt + N);            // N*32 f32 (reused as h2)
    u16*   skip2b  = (u16*)(h1 + N * 32);           // N*32 bf16 (reused as ek3b)
    u16*   bg2b    = skip2b + N * 32;               // N*64 bf16 (reused as qvb)
    u16*   xlb     = bg2b + N * 64;                 // N*32 bf16
    float* acc3    = (float*)(xlb + N * 32);        // N*32 f32

    hipMemsetAsync(gcnt, 0, 256 * sizeof(int) + N_GRAPH * 32 * sizeof(float), stream);

    const int TB = 256;
    int gPart  = (N_EDGES + 256 * PEPT - 1) / (256 * PEPT);  // 391
    int gNode8 = (N_NODES * 8) / TB;                         // 3125 exact
    int gFin   = (N_GRAPH * 10 + TB - 1) / TB;               // 40

    // CSR build
    k_partition<<<gPart, TB, 0, stream>>>(ei, gcnt, bucketed);
    k_bscan<<<1, 256, 0, stream>>>(gcnt, bbase);
    k_place<<<NB, 512, 0, stream>>>(bucketed, gcnt, bbase, icsr, istarts, icnt);
    k_gstart<<<5, TB, 0, stream>>>(batch, igstart);

    // Layer 1: x-direct gather (x L2-resident; exp inline, rcp sigmoid)
    k_gath1<<<gNode8, TB, 0, stream>>>(x, icsr, istarts, icnt,
                                       c1_Wk, c1_bk, c1_Wq, c1_bq,
                                       c1_Wv, c1_bv, c1_Wsk, c1_b, h1);
    // Layer 2 (FiLM, bf16 dst-side streams)
    k_node2<<<gNode8, TB, 0, stream>>>(h1, c2_Wlin, c2_Wfilm, c2_bfilm,
                                       c2_Wls, c2_Wfs, skip2b, bg2b, xlb);
    float* h2 = h1;
    k_gath2<<<gNode8, TB, 0, stream>>>(icsr, istarts, icnt, bg2b, xlb, skip2b, h2);
    // Layer 3 (ResGated, exp-hoisted) + fused mean-pool
    u16* ek3b = skip2b;
    u32* qvb  = (u32*)bg2b;
    k_node3<<<gNode8, TB, 0, stream>>>(h2, c3_Wk, c3_bk, c3_Wq, c3_bq,
                                       c3_Wv, c3_bv, c3_Wsk, c3_b,
                                       ek3b, qvb, acc3);
    k_gath3p<<<gNode8, TB, 0, stream>>>(icsr, istarts, icnt, ek3b, qvb, acc3,
                                        batch, gsum);
    // classifier
    k_final<<<gFin, TB, 0, stream>>>(gsum, igstart, lin_W, lin_b, out);
}